// Round 5
// baseline (1110.475 us; speedup 1.0000x reference)
//
#include <hip/hip_runtime.h>
#include <hip/hip_cooperative_groups.h>
#include <math.h>

namespace cg = cooperative_groups;

#define NND 4096
#define SDIM 128
#define HEADS 4
#define D1 64
#define HID 256
#define D2 256
#define C2 1024
#define NP1 (NND + 1)
#define CH1 128
#define CHR1 32
#define CH2 128
#define CHR2 32
#define LEAKY 0.2f
#define LN_EPS 1e-5f
#define LDA 40
#define NB 512

typedef __attribute__((ext_vector_type(8))) short bf16x8;
typedef __attribute__((ext_vector_type(4))) float f32x4;
typedef __attribute__((ext_vector_type(8))) unsigned short u16x8;
typedef __attribute__((ext_vector_type(4))) unsigned short u16x4;

union SMem {
    struct {
        unsigned short Ah[64][LDA], Al[64][LDA], Bh[64][LDA], Bl[64][LDA];
        float esP[2][2][32], etP[2][2][32];
    } g;
    struct { unsigned key[NND]; int pr[64]; } s;
    struct { float wa[HEADS][CHR1], wb[HEADS][CHR1]; } w;
    struct { float sA[4], sB[4]; } wp;
    struct { float red2[4][8]; } l1;
    struct { float red[4]; } l2;
};

struct MegaParams {
    const float *x, *W1, *attn1, *W2, *attn2, *gamma, *betap;
    float *out;
    unsigned short *W1h, *W1l, *W2h, *W2l;
    float *w_es, *w_et;
    float *Wx1, *Wx2, *h1;
    float *es1, *et1, *es2, *et2, *ts1, *ts2;
    int *perm1, *perm2;
    float *A, *B, *SA, *SB, *cTA, *cTB;
};

__device__ __forceinline__ unsigned short f2bf(float f) {
    union { float f; unsigned u; } v; v.f = f;
    unsigned r = v.u + 0x7FFFu + ((v.u >> 16) & 1u);
    return (unsigned short)(r >> 16);
}
__device__ __forceinline__ float bf2f(unsigned short s) {
    union { unsigned u; float f; } v; v.u = ((unsigned)s) << 16; return v.f;
}
__device__ __forceinline__ float wave_sum(float v) {
#pragma unroll
    for (int o = 32; o > 0; o >>= 1) v += __shfl_xor(v, o, 64);
    return v;
}
__device__ __forceinline__ int lower_bound_f(const float* __restrict__ a, float x) {
    int lo = 0, hi = NND;
    while (lo < hi) {
        int mid = (lo + hi) >> 1;
        if (a[mid] < x) lo = mid + 1; else hi = mid;
    }
    return lo;
}

#define MM(a, b, c) c = __builtin_amdgcn_mfma_f32_16x16x32_bf16(a, b, c, 0, 0, 0)

// ---------------- MFMA split-bf16 64x64 GEMM tile; ES fuses escore1 ----------------
template<bool ES>
__device__ __forceinline__ void gemm_tile(const MegaParams& P, SMem& sm,
        const float* __restrict__ Ag, int Astr,
        const unsigned short* __restrict__ Wh, const unsigned short* __restrict__ Wl,
        int K, int n0, int m0, float* __restrict__ Cg, int Cstr, int h, int t) {
    const int lane = t & 63, w = t >> 6;
    const int wm = w >> 1, wn = w & 1;
    const int fr = lane & 15, kg = lane >> 4;
    f32x4 z4 = {0.f, 0.f, 0.f, 0.f};
    f32x4 acc[2][2] = {{z4, z4}, {z4, z4}};
    for (int k0 = 0; k0 < K; k0 += 32) {
#pragma unroll
        for (int q = 0; q < 2; q++) {
            int p = t + 256 * q, r = p >> 3, kq = (p & 7) * 4;
            float4 av = *(const float4*)&Ag[(size_t)(m0 + r) * Astr + k0 + kq];
            float fv[4] = {av.x, av.y, av.z, av.w};
            unsigned short hi4[4], lo4[4];
#pragma unroll
            for (int i2 = 0; i2 < 4; i2++) {
                hi4[i2] = f2bf(fv[i2]);
                lo4[i2] = f2bf(fv[i2] - bf2f(hi4[i2]));
            }
            *(u16x4*)&sm.g.Ah[r][kq] = (u16x4){hi4[0], hi4[1], hi4[2], hi4[3]};
            *(u16x4*)&sm.g.Al[r][kq] = (u16x4){lo4[0], lo4[1], lo4[2], lo4[3]};
        }
        {
            int r = t >> 2, kq = (t & 3) * 8;
            *(u16x8*)&sm.g.Bh[r][kq] = *(const u16x8*)&Wh[(size_t)(n0 + r) * K + k0 + kq];
            *(u16x8*)&sm.g.Bl[r][kq] = *(const u16x8*)&Wl[(size_t)(n0 + r) * K + k0 + kq];
        }
        __syncthreads();
        bf16x8 ah0 = *(bf16x8*)&sm.g.Ah[wm * 32 + fr][kg * 8];
        bf16x8 ah1 = *(bf16x8*)&sm.g.Ah[wm * 32 + 16 + fr][kg * 8];
        bf16x8 al0 = *(bf16x8*)&sm.g.Al[wm * 32 + fr][kg * 8];
        bf16x8 al1 = *(bf16x8*)&sm.g.Al[wm * 32 + 16 + fr][kg * 8];
        bf16x8 bh0 = *(bf16x8*)&sm.g.Bh[wn * 32 + fr][kg * 8];
        bf16x8 bh1 = *(bf16x8*)&sm.g.Bh[wn * 32 + 16 + fr][kg * 8];
        bf16x8 bl0 = *(bf16x8*)&sm.g.Bl[wn * 32 + fr][kg * 8];
        bf16x8 bl1 = *(bf16x8*)&sm.g.Bl[wn * 32 + 16 + fr][kg * 8];
        MM(ah0, bh0, acc[0][0]); MM(ah0, bl0, acc[0][0]); MM(al0, bh0, acc[0][0]);
        MM(ah0, bh1, acc[0][1]); MM(ah0, bl1, acc[0][1]); MM(al0, bh1, acc[0][1]);
        MM(ah1, bh0, acc[1][0]); MM(ah1, bl0, acc[1][0]); MM(al1, bh0, acc[1][0]);
        MM(ah1, bh1, acc[1][1]); MM(ah1, bl1, acc[1][1]); MM(al1, bh1, acc[1][1]);
        __syncthreads();
    }
    if constexpr (ES) {
        const float as0 = P.attn1[h * 128 + wn * 32 + fr];
        const float as1 = P.attn1[h * 128 + wn * 32 + 16 + fr];
        const float at0 = P.attn1[h * 128 + 64 + wn * 32 + fr];
        const float at1 = P.attn1[h * 128 + 64 + wn * 32 + 16 + fr];
#pragma unroll
        for (int mb = 0; mb < 2; mb++) {
#pragma unroll
            for (int r = 0; r < 4; r++) {
                int row = m0 + wm * 32 + mb * 16 + kg * 4 + r;
#pragma unroll
                for (int nb = 0; nb < 2; nb++)
                    Cg[(size_t)row * Cstr + n0 + wn * 32 + nb * 16 + fr] = acc[mb][nb][r];
                float ve = acc[mb][0][r] * as0 + acc[mb][1][r] * as1;
                float vt = acc[mb][0][r] * at0 + acc[mb][1][r] * at1;
#pragma unroll
                for (int msk = 1; msk < 16; msk <<= 1) {
                    ve += __shfl_xor(ve, msk, 64);
                    vt += __shfl_xor(vt, msk, 64);
                }
                if (fr == 0) {
                    sm.g.esP[wm][wn][mb * 16 + kg * 4 + r] = ve;
                    sm.g.etP[wm][wn][mb * 16 + kg * 4 + r] = vt;
                }
            }
        }
        __syncthreads();
        if (t < 64) {
            int wmm = t >> 5, ri = t & 31;
            P.es1[h * NND + m0 + t] = sm.g.esP[wmm][0][ri] + sm.g.esP[wmm][1][ri];
            P.et1[h * NND + m0 + t] = sm.g.etP[wmm][0][ri] + sm.g.etP[wmm][1][ri];
        }
    } else {
#pragma unroll
        for (int mb = 0; mb < 2; mb++)
#pragma unroll
            for (int r = 0; r < 4; r++) {
                int row = m0 + wm * 32 + mb * 16 + kg * 4 + r;
#pragma unroll
                for (int nb = 0; nb < 2; nb++)
                    Cg[(size_t)row * Cstr + n0 + wn * 32 + nb * 16 + fr] = acc[mb][nb][r];
            }
    }
}

// ---------------- rank sort of 64 elems/block against all keys (sortable-uint) ----------------
__device__ __forceinline__ void sort_block(SMem& sm, const float* __restrict__ et,
        float* __restrict__ ts, int* __restrict__ perm, int h, int e0, int t) {
    for (int p = t; p < NND; p += 256) {
        unsigned u = __float_as_uint(et[h * NND + p]);
        sm.s.key[p] = (u & 0x80000000u) ? ~u : (u | 0x80000000u);
    }
    if (t < 64) sm.s.pr[t] = 0;
    __syncthreads();
    const int e = t & 63, sg = t >> 6;
    const int myIdx = e0 + e;
    const unsigned myU = sm.s.key[myIdx];
    int rank = 0;
    const int kbeg = sg * (NND / 4);
#pragma unroll 8
    for (int k = kbeg; k < kbeg + NND / 4; k++) {
        unsigned v = sm.s.key[k];
        rank += (v < myU || (v == myU && k < myIdx)) ? 1 : 0;
    }
    atomicAdd(&sm.s.pr[e], rank);
    __syncthreads();
    if (t < 64) {
        int r = sm.s.pr[t];
        unsigned u = sm.s.key[e0 + t];
        float f = (u & 0x80000000u) ? __uint_as_float(u ^ 0x80000000u)
                                    : __uint_as_float(~u);
        ts[h * NND + r] = f;
        perm[h * NND + r] = e0 + t;
    }
    __syncthreads();
}

// ---------------- per-head scalar weight scan: SA (suffix incl), SB (prefix excl) ----------------
__device__ __forceinline__ void wprep_block(SMem& sm, const float* __restrict__ ts,
        float* __restrict__ SA, float* __restrict__ SB, int h, int t) {
    const int lane = t & 63, w = t >> 6;
    const float tmax = ts[h * NND + NND - 1];
    float a[16], b[16];
    float la = 0.f, lb = 0.f;
    const int kb = t * 16;
#pragma unroll
    for (int q = 0; q < 16; q++) {
        float u = ts[h * NND + kb + q] - tmax;
        a[q] = expf(u); b[q] = expf(LEAKY * u);
        la += a[q]; lb += b[q];
    }
    float sa = la, sb = lb;
#pragma unroll
    for (int o = 1; o < 64; o <<= 1) {
        float ua = __shfl_up(sa, o, 64);
        float ub = __shfl_up(sb, o, 64);
        if (lane >= o) { sa += ua; sb += ub; }
    }
    if (lane == 63) { sm.wp.sA[w] = sa; sm.wp.sB[w] = sb; }
    __syncthreads();
    float baseA = 0.f, baseB = 0.f, totA = 0.f, totB = 0.f;
#pragma unroll
    for (int ww = 0; ww < 4; ww++) {
        float va = sm.wp.sA[ww], vb = sm.wp.sB[ww];
        totA += va; totB += vb;
        if (ww < w) { baseA += va; baseB += vb; }
    }
    float preA = baseA + sa - la;
    float preB = baseB + sb - lb;
#pragma unroll
    for (int q = 0; q < 16; q++) {
        SA[h * NP1 + kb + q] = totA - preA;
        SB[h * NP1 + kb + q] = preB;
        preA += a[q]; preB += b[q];
    }
    if (t == 255) { SA[h * NP1 + NND] = 0.f; SB[h * NP1 + NND] = totB; }
    __syncthreads();
}

__device__ __forceinline__ void weights4(SMem& sm, const float* __restrict__ ts, int k0, int t) {
    if (t < 128) {
        int hh = t >> 5, r = t & 31;
        float tmax = ts[hh * NND + NND - 1];
        float u = ts[hh * NND + k0 + r] - tmax;
        sm.w.wa[hh][r] = expf(u);
        sm.w.wb[hh][r] = expf(LEAKY * u);
    }
    __syncthreads();
}
__device__ __forceinline__ void weights1(SMem& sm, const float* __restrict__ ts, int h, int k0, int t) {
    if (t < 32) {
        float tmax = ts[h * NND + NND - 1];
        float u = ts[h * NND + k0 + t] - tmax;
        sm.w.wa[0][t] = expf(u);
        sm.w.wb[0][t] = expf(LEAKY * u);
    }
    __syncthreads();
}

__device__ __forceinline__ void scan1_p1(const MegaParams& P, SMem& sm, int ch, int t) {
    weights4(sm, P.ts1, ch * CHR1, t);
    const int h = t >> 6, d = t & 63;
    const int k0 = ch * CHR1;
    float aA = 0.f, aB = 0.f;
#pragma unroll
    for (int r = 0; r < CHR1; r++) {
        int j = P.perm1[h * NND + k0 + r];
        float v = P.Wx1[(size_t)j * HID + h * D1 + d];
        aA += sm.w.wa[h][r] * v;
        aB += sm.w.wb[h][r] * v;
    }
    P.cTA[(h * CH1 + ch) * D1 + d] = aA;
    P.cTB[(h * CH1 + ch) * D1 + d] = aB;
}

__device__ __forceinline__ void scan1_p3(const MegaParams& P, SMem& sm, int ch, int t) {
    weights4(sm, P.ts1, ch * CHR1, t);
    const int h = t >> 6, d = t & 63;
    float runA = 0.f, runB = 0.f, totA = 0.f, totB = 0.f;
#pragma unroll 8
    for (int c = 0; c < CH1; c++) {
        float vA = P.cTA[(h * CH1 + c) * D1 + d];
        float vB = P.cTB[(h * CH1 + c) * D1 + d];
        totA += vA; totB += vB;
        if (c < ch) { runA += vA; runB += vB; }
    }
    const int k0 = ch * CHR1;
    float v[CHR1];
#pragma unroll
    for (int r = 0; r < CHR1; r++) {
        int j = P.perm1[h * NND + k0 + r];
        v[r] = P.Wx1[(size_t)j * HID + h * D1 + d];
    }
#pragma unroll
    for (int r = 0; r < CHR1; r++) {
        size_t o = ((size_t)(h * NP1 + k0 + r)) * D1 + d;
        P.A[o] = totA - runA;
        P.B[o] = runB;
        runA += sm.w.wa[h][r] * v[r];
        runB += sm.w.wb[h][r] * v[r];
    }
    if (ch == CH1 - 1) {
        size_t o = ((size_t)(h * NP1 + NND)) * D1 + d;
        P.A[o] = totA - runA;
        P.B[o] = runB;
    }
}

__device__ __forceinline__ void scan2_p1(const MegaParams& P, SMem& sm, int ch, int h, int t) {
    weights1(sm, P.ts2, h, ch * CHR2, t);
    const int d = t;
    const int k0 = ch * CHR2;
    float aA = 0.f, aB = 0.f;
#pragma unroll
    for (int r = 0; r < CHR2; r++) {
        int j = P.perm2[h * NND + k0 + r];
        float v = P.Wx2[(size_t)j * C2 + h * D2 + d];
        aA += sm.w.wa[0][r] * v;
        aB += sm.w.wb[0][r] * v;
    }
    P.cTA[(h * CH2 + ch) * D2 + d] = aA;
    P.cTB[(h * CH2 + ch) * D2 + d] = aB;
}

__device__ __forceinline__ void scan2_p3(const MegaParams& P, SMem& sm, int ch, int h, int t) {
    weights1(sm, P.ts2, h, ch * CHR2, t);
    const int d = t;
    float runA = 0.f, runB = 0.f, totA = 0.f, totB = 0.f;
#pragma unroll 8
    for (int c = 0; c < CH2; c++) {
        float vA = P.cTA[(h * CH2 + c) * D2 + d];
        float vB = P.cTB[(h * CH2 + c) * D2 + d];
        totA += vA; totB += vB;
        if (c < ch) { runA += vA; runB += vB; }
    }
    const int k0 = ch * CHR2;
    float v[CHR2];
#pragma unroll
    for (int r = 0; r < CHR2; r++) {
        int j = P.perm2[h * NND + k0 + r];
        v[r] = P.Wx2[(size_t)j * C2 + h * D2 + d];
    }
#pragma unroll
    for (int r = 0; r < CHR2; r++) {
        size_t o = ((size_t)(h * NP1 + k0 + r)) * D2 + d;
        P.A[o] = totA - runA;
        P.B[o] = runB;
        runA += sm.w.wa[0][r] * v[r];
        runB += sm.w.wb[0][r] * v[r];
    }
    if (ch == CH2 - 1) {
        size_t o = ((size_t)(h * NP1 + NND)) * D2 + d;
        P.A[o] = totA - runA;
        P.B[o] = runB;
    }
}

__device__ __forceinline__ void lookup1_row(const MegaParams& P, SMem& sm, int i, int t) {
    const int h = t >> 6, d = t & 63;
    const int lane = t & 63, wid = t >> 6;
    float c = P.es1[h * NND + i];
    float tmax = P.ts1[h * NND + NND - 1];
    float s = c + tmax;
    float m = (s >= 0.f) ? s : LEAKY * s;
    float al = expf(s - m);
    float be = expf(LEAKY * s - m);
    int k = lower_bound_f(P.ts1 + h * NND, -c);
    size_t o = ((size_t)(h * NP1 + k)) * D1 + d;
    float num = al * P.A[o] + be * P.B[o];
    float den = al * P.SA[h * NP1 + k] + be * P.SB[h * NP1 + k];
    float val = num / den;
    float hv = (val > 0.f) ? val : expm1f(val);
    P.h1[i * HID + t] = hv;
#pragma unroll
    for (int oo = 0; oo < 8; oo++) {
        int hh = oo >> 1;
        const float* wv = (oo & 1) ? P.w_et : P.w_es;
        float p = hv * wv[hh * HID + t];
        p = wave_sum(p);
        if (lane == 0) sm.l1.red2[wid][oo] = p;
    }
    __syncthreads();
    if (t < 8) {
        float sv = sm.l1.red2[0][t] + sm.l1.red2[1][t] + sm.l1.red2[2][t] + sm.l1.red2[3][t];
        int hh = t >> 1;
        if (t & 1) P.et2[hh * NND + i] = sv;
        else       P.es2[hh * NND + i] = sv;
    }
    __syncthreads();
}

__device__ __forceinline__ void lookup2_row(const MegaParams& P, SMem& sm, int i, int t) {
    const int wid = t >> 6, lane = t & 63;
    float acc = 0.f;
#pragma unroll
    for (int h = 0; h < HEADS; h++) {
        float c = P.es2[h * NND + i];
        float tmax = P.ts2[h * NND + NND - 1];
        float s = c + tmax;
        float m = (s >= 0.f) ? s : LEAKY * s;
        float al = expf(s - m);
        float be = expf(LEAKY * s - m);
        int k = lower_bound_f(P.ts2 + h * NND, -c);
        size_t o = ((size_t)(h * NP1 + k)) * D2 + t;
        float num = al * P.A[o] + be * P.B[o];
        float den = al * P.SA[h * NP1 + k] + be * P.SB[h * NP1 + k];
        acc += num / den;
    }
    acc *= 0.25f;
    float xv = (acc > 0.f) ? acc : expm1f(acc);
    float sv = wave_sum(xv);
    if (lane == 0) sm.l2.red[wid] = sv;
    __syncthreads();
    float mu = (sm.l2.red[0] + sm.l2.red[1] + sm.l2.red[2] + sm.l2.red[3]) * (1.f / 256.f);
    __syncthreads();
    float dv = xv - mu;
    float s2 = wave_sum(dv * dv);
    if (lane == 0) sm.l2.red[wid] = s2;
    __syncthreads();
    float var = (sm.l2.red[0] + sm.l2.red[1] + sm.l2.red[2] + sm.l2.red[3]) * (1.f / 256.f);
    P.out[i * D2 + t] = P.gamma[t] * dv * rsqrtf(var + LN_EPS) + P.betap[t];
    __syncthreads();
}

__global__ __launch_bounds__(256, 2) void mega_k(MegaParams P) {
    __shared__ SMem sm;
    cg::grid_group grid = cg::this_grid();
    const int bid = blockIdx.x, t = threadIdx.x;

    // P0: W1 -> bf16 hi/lo [n][k]
    for (int vb = bid; vb < 128; vb += NB) {
        int id = vb * 256 + t;
        int n = id >> 7, k = id & 127;
        float v = P.W1[k * HID + n];
        unsigned short hi = f2bf(v);
        P.W1h[id] = hi; P.W1l[id] = f2bf(v - bf2f(hi));
    }
    __threadfence(); grid.sync();

    // P1: gemm1(+escore1) | W2 prep | w_es/w_et fold
    for (int vb = bid; vb < 1792; vb += NB) {
        if (vb < 256) {
            gemm_tile<true>(P, sm, P.x, SDIM, P.W1h, P.W1l, SDIM,
                            (vb & 3) * 64, (vb >> 2) * 64, P.Wx1, HID, vb & 3, t);
        } else if (vb < 1280) {
            int j = (vb - 256) * 256 + t;
            int n = j >> 8, k = j & 255;
            float v = P.W2[(size_t)k * C2 + n];
            unsigned short hi = f2bf(v);
            P.W2h[j] = hi; P.W2l[j] = f2bf(v - bf2f(hi));
        } else {
            int g = (vb - 1280) * 4 + (t >> 6);
            int lane = t & 63;
            int k = g & 255, hs = g >> 8, h = hs >> 1, sel = hs & 1;
            float acc = 0.f;
#pragma unroll
            for (int qq = 0; qq < 4; qq++)
                acc += P.W2[(size_t)k * C2 + h * 256 + qq * 64 + lane] *
                       P.attn2[h * 512 + sel * 256 + qq * 64 + lane];
            acc = wave_sum(acc);
            if (lane == 0) {
                if (sel) P.w_et[h * 256 + k] = acc;
                else     P.w_es[h * 256 + k] = acc;
            }
        }
    }
    __threadfence(); grid.sync();

    // P2: sort layer 1
    if (bid < 256) sort_block(sm, P.et1, P.ts1, P.perm1, bid >> 6, (bid & 63) * 64, t);
    __threadfence(); grid.sync();

    // P3: wprep1 | scan1_p1
    if (bid < 4) wprep_block(sm, P.ts1, P.SA, P.SB, bid, t);
    else if (bid < 4 + CH1) scan1_p1(P, sm, bid - 4, t);
    __threadfence(); grid.sync();

    // P4: scan1_p3
    if (bid < CH1) scan1_p3(P, sm, bid, t);
    __threadfence(); grid.sync();

    // P5: lookup1 + fused escore2
    for (int i = bid; i < NND; i += NB) lookup1_row(P, sm, i, t);
    __threadfence(); grid.sync();

    // P6: gemm2 | sort layer 2
    for (int vb = bid; vb < 1280; vb += NB) {
        if (vb < 1024)
            gemm_tile<false>(P, sm, P.h1, HID, P.W2h, P.W2l, HID,
                             (vb & 15) * 64, (vb >> 4) * 64, P.Wx2, C2, 0, t);
        else
            sort_block(sm, P.et2, P.ts2, P.perm2, (vb - 1024) >> 6, ((vb - 1024) & 63) * 64, t);
    }
    __threadfence(); grid.sync();

    // P7: wprep2 | scan2_p1
    for (int vb = bid; vb < 4 + CH2 * HEADS; vb += NB) {
        if (vb < 4) wprep_block(sm, P.ts2, P.SA, P.SB, vb, t);
        else scan2_p1(P, sm, (vb - 4) & 127, (vb - 4) >> 7, t);
    }
    __threadfence(); grid.sync();

    // P8: scan2_p3
    scan2_p3(P, sm, bid & 127, bid >> 7, t);
    __threadfence(); grid.sync();

    // P9: lookup2 (head-mean + ELU + LayerNorm)
    for (int i = bid; i < NND; i += NB) lookup2_row(P, sm, i, t);
}

extern "C" void kernel_launch(void* const* d_in, const int* in_sizes, int n_in,
                              void* d_out, int out_size, void* d_ws, size_t ws_size,
                              hipStream_t stream) {
    char* ws = (char*)d_ws;
    size_t off = 0;
    auto alloc = [&](size_t nbytes) -> void* {
        void* p = (void*)(ws + off);
        off += (nbytes + 255) & ~(size_t)255;
        return p;
    };

    MegaParams P;
    P.x     = (const float*)d_in[0];
    P.W1    = (const float*)d_in[1];
    P.attn1 = (const float*)d_in[2];
    P.W2    = (const float*)d_in[3];
    P.attn2 = (const float*)d_in[4];
    P.gamma = (const float*)d_in[5];
    P.betap = (const float*)d_in[6];
    P.out   = (float*)d_out;

    P.Wx1 = (float*)alloc((size_t)NND * HID * 4);
    P.Wx2 = (float*)alloc((size_t)NND * C2 * 4);
    P.h1  = (float*)alloc((size_t)NND * HID * 4);
    P.es1 = (float*)alloc((size_t)HEADS * NND * 4);
    P.et1 = (float*)alloc((size_t)HEADS * NND * 4);
    P.es2 = (float*)alloc((size_t)HEADS * NND * 4);
    P.et2 = (float*)alloc((size_t)HEADS * NND * 4);
    P.ts1 = (float*)alloc((size_t)HEADS * NND * 4);
    P.ts2 = (float*)alloc((size_t)HEADS * NND * 4);
    P.perm1 = (int*)alloc((size_t)HEADS * NND * 4);
    P.perm2 = (int*)alloc((size_t)HEADS * NND * 4);
    P.A   = (float*)alloc((size_t)HEADS * NP1 * D2 * 4);
    P.B   = (float*)alloc((size_t)HEADS * NP1 * D2 * 4);
    P.SA  = (float*)alloc((size_t)HEADS * NP1 * 4);
    P.SB  = (float*)alloc((size_t)HEADS * NP1 * 4);
    P.cTA = (float*)alloc((size_t)131072 * 4);
    P.cTB = (float*)alloc((size_t)131072 * 4);
    P.W1h = (unsigned short*)alloc((size_t)32768 * 2);
    P.W1l = (unsigned short*)alloc((size_t)32768 * 2);
    P.W2h = (unsigned short*)alloc((size_t)262144 * 2);
    P.W2l = (unsigned short*)alloc((size_t)262144 * 2);
    P.w_es = (float*)alloc((size_t)HEADS * HID * 4);
    P.w_et = (float*)alloc((size_t)HEADS * HID * 4);
    (void)ws_size; (void)in_sizes; (void)n_in; (void)out_size;

    void* args[] = {&P};
    hipLaunchCooperativeKernel((void*)mega_k, dim3(NB), dim3(256), args, 0, stream);
}

// Round 6
// 326.160 us; speedup vs baseline: 3.4047x; 3.4047x over previous
//
#include <hip/hip_runtime.h>
#include <math.h>

#define NND 4096
#define SDIM 128
#define HEADS 4
#define D1 64
#define HID 256
#define D2 256
#define C2 1024
#define NP1 (NND + 1)
#define CH 512
#define CHR 8
#define LEAKY 0.2f
#define LN_EPS 1e-5f
#define LDA 40

typedef __attribute__((ext_vector_type(8))) short bf16x8;
typedef __attribute__((ext_vector_type(4))) float f32x4;
typedef __attribute__((ext_vector_type(8))) unsigned short u16x8;
typedef __attribute__((ext_vector_type(4))) unsigned short u16x4;

union SMem {
    struct {
        unsigned short Ah[64][LDA], Al[64][LDA], Bh[64][LDA], Bl[64][LDA];
        float esP[2][2][32], etP[2][2][32];
    } g;
    struct { unsigned key[NND]; int pr[64]; } s;
};

__device__ __forceinline__ unsigned short f2bf(float f) {
    union { float f; unsigned u; } v; v.f = f;
    unsigned r = v.u + 0x7FFFu + ((v.u >> 16) & 1u);
    return (unsigned short)(r >> 16);
}
__device__ __forceinline__ float bf2f(unsigned short s) {
    union { unsigned u; float f; } v; v.u = ((unsigned)s) << 16; return v.f;
}
__device__ __forceinline__ float wave_sum(float v) {
#pragma unroll
    for (int o = 32; o > 0; o >>= 1) v += __shfl_xor(v, o, 64);
    return v;
}
__device__ __forceinline__ int lower_bound_f(const float* __restrict__ a, float x) {
    int lo = 0, hi = NND;
    while (lo < hi) {
        int mid = (lo + hi) >> 1;
        if (a[mid] < x) lo = mid + 1; else hi = mid;
    }
    return lo;
}

#define MM(a, b, c) c = __builtin_amdgcn_mfma_f32_16x16x32_bf16(a, b, c, 0, 0, 0)

// ---------------- sort: rank of 64 elems/block vs all keys (sortable uint) ----------------
__device__ __forceinline__ void sort_block(SMem& sm, const float* __restrict__ et,
        float* __restrict__ ts, int* __restrict__ perm, int h, int e0, int t) {
    for (int p = t; p < NND; p += 256) {
        unsigned u = __float_as_uint(et[h * NND + p]);
        sm.s.key[p] = (u & 0x80000000u) ? ~u : (u | 0x80000000u);
    }
    if (t < 64) sm.s.pr[t] = 0;
    __syncthreads();
    const int e = t & 63, sg = t >> 6;
    const int myIdx = e0 + e;
    const unsigned myU = sm.s.key[myIdx];
    int rank = 0;
    const int kbeg = sg * (NND / 4);
#pragma unroll 8
    for (int k = kbeg; k < kbeg + NND / 4; k++) {
        unsigned v = sm.s.key[k];
        rank += (v < myU || (v == myU && k < myIdx)) ? 1 : 0;
    }
    atomicAdd(&sm.s.pr[e], rank);
    __syncthreads();
    if (t < 64) {
        int r = sm.s.pr[t];
        unsigned u = sm.s.key[e0 + t];
        float f = (u & 0x80000000u) ? __uint_as_float(u ^ 0x80000000u)
                                    : __uint_as_float(~u);
        ts[h * NND + r] = f;
        perm[h * NND + r] = e0 + t;
    }
}

// ---------------- per-head scalar weight scan: SA (suffix incl), SB (prefix excl) --------
__device__ __forceinline__ void wprep_block(const float* __restrict__ ts,
        float* __restrict__ SA, float* __restrict__ SB, int h, int t,
        float* swA, float* swB) {
    const int lane = t & 63, w = t >> 6;
    const float tmax = ts[h * NND + NND - 1];
    float a[16], b[16];
    float la = 0.f, lb = 0.f;
    const int kb = t * 16;
#pragma unroll
    for (int q = 0; q < 16; q++) {
        float u = ts[h * NND + kb + q] - tmax;
        a[q] = expf(u); b[q] = expf(LEAKY * u);
        la += a[q]; lb += b[q];
    }
    float sa = la, sb = lb;
#pragma unroll
    for (int o = 1; o < 64; o <<= 1) {
        float ua = __shfl_up(sa, o, 64);
        float ub = __shfl_up(sb, o, 64);
        if (lane >= o) { sa += ua; sb += ub; }
    }
    if (lane == 63) { swA[w] = sa; swB[w] = sb; }
    __syncthreads();
    float baseA = 0.f, baseB = 0.f, totA = 0.f, totB = 0.f;
#pragma unroll
    for (int ww = 0; ww < 4; ww++) {
        float va = swA[ww], vb = swB[ww];
        totA += va; totB += vb;
        if (ww < w) { baseA += va; baseB += vb; }
    }
    float preA = baseA + sa - la;
    float preB = baseB + sb - lb;
#pragma unroll
    for (int q = 0; q < 16; q++) {
        SA[h * NP1 + kb + q] = totA - preA;
        SB[h * NP1 + kb + q] = preB;
        preA += a[q]; preB += b[q];
    }
    if (t == 255) { SA[h * NP1 + NND] = 0.f; SB[h * NP1 + NND] = totB; }
}

// ---------------- k1: gemm1 (inline W1 split, fused escore1) | W2 prep | attn2 fold ------
__global__ __launch_bounds__(256) void k1_gemm1_prep(
        const float* __restrict__ x, const float* __restrict__ W1,
        const float* __restrict__ attn1,
        const float* __restrict__ W2, const float* __restrict__ attn2,
        float* __restrict__ Wx1, float* __restrict__ es1, float* __restrict__ et1,
        unsigned short* __restrict__ W2h, unsigned short* __restrict__ W2l,
        float* __restrict__ w_es, float* __restrict__ w_et) {
    __shared__ SMem sm;
    const int bid = blockIdx.x, t = threadIdx.x;
    if (bid < 256) {
        const int lane = t & 63, w = t >> 6;
        const int wm = w >> 1, wn = w & 1;
        const int h = bid & 3, n0 = h * 64, m0 = (bid >> 2) * 64;
        const int fr = lane & 15, kg = lane >> 4;
        f32x4 z4 = {0.f, 0.f, 0.f, 0.f};
        f32x4 acc[2][2] = {{z4, z4}, {z4, z4}};
        for (int k0 = 0; k0 < SDIM; k0 += 32) {
#pragma unroll
            for (int q = 0; q < 2; q++) {
                int p = t + 256 * q, r = p >> 3, kk = (p & 7) * 4;
                float4 av = *(const float4*)&x[(size_t)(m0 + r) * SDIM + k0 + kk];
                float fv[4] = {av.x, av.y, av.z, av.w};
                unsigned short hi4[4], lo4[4];
#pragma unroll
                for (int i = 0; i < 4; i++) {
                    hi4[i] = f2bf(fv[i]);
                    lo4[i] = f2bf(fv[i] - bf2f(hi4[i]));
                }
                *(u16x4*)&sm.g.Ah[r][kk] = (u16x4){hi4[0], hi4[1], hi4[2], hi4[3]};
                *(u16x4*)&sm.g.Al[r][kk] = (u16x4){lo4[0], lo4[1], lo4[2], lo4[3]};
            }
            {
                const int kq4 = t >> 6;
                unsigned short bh[8], bl[8];
#pragma unroll
                for (int i = 0; i < 8; i++) {
                    float v = W1[(size_t)(k0 + kq4 * 8 + i) * HID + n0 + lane];
                    bh[i] = f2bf(v);
                    bl[i] = f2bf(v - bf2f(bh[i]));
                }
                u16x8 ph, pl;
#pragma unroll
                for (int i = 0; i < 8; i++) { ph[i] = bh[i]; pl[i] = bl[i]; }
                *(u16x8*)&sm.g.Bh[lane][kq4 * 8] = ph;
                *(u16x8*)&sm.g.Bl[lane][kq4 * 8] = pl;
            }
            __syncthreads();
            bf16x8 ah0 = *(bf16x8*)&sm.g.Ah[wm * 32 + fr][kg * 8];
            bf16x8 ah1 = *(bf16x8*)&sm.g.Ah[wm * 32 + 16 + fr][kg * 8];
            bf16x8 al0 = *(bf16x8*)&sm.g.Al[wm * 32 + fr][kg * 8];
            bf16x8 al1 = *(bf16x8*)&sm.g.Al[wm * 32 + 16 + fr][kg * 8];
            bf16x8 bh0 = *(bf16x8*)&sm.g.Bh[wn * 32 + fr][kg * 8];
            bf16x8 bh1 = *(bf16x8*)&sm.g.Bh[wn * 32 + 16 + fr][kg * 8];
            bf16x8 bl0 = *(bf16x8*)&sm.g.Bl[wn * 32 + fr][kg * 8];
            bf16x8 bl1 = *(bf16x8*)&sm.g.Bl[wn * 32 + 16 + fr][kg * 8];
            MM(ah0, bh0, acc[0][0]); MM(ah0, bl0, acc[0][0]); MM(al0, bh0, acc[0][0]);
            MM(ah0, bh1, acc[0][1]); MM(ah0, bl1, acc[0][1]); MM(al0, bh1, acc[0][1]);
            MM(ah1, bh0, acc[1][0]); MM(ah1, bl0, acc[1][0]); MM(al1, bh0, acc[1][0]);
            MM(ah1, bh1, acc[1][1]); MM(ah1, bl1, acc[1][1]); MM(al1, bh1, acc[1][1]);
            __syncthreads();
        }
        const float as0 = attn1[h * 128 + wn * 32 + fr];
        const float as1 = attn1[h * 128 + wn * 32 + 16 + fr];
        const float at0 = attn1[h * 128 + 64 + wn * 32 + fr];
        const float at1 = attn1[h * 128 + 64 + wn * 32 + 16 + fr];
#pragma unroll
        for (int mb = 0; mb < 2; mb++) {
#pragma unroll
            for (int r = 0; r < 4; r++) {
                int row = m0 + wm * 32 + mb * 16 + kg * 4 + r;
#pragma unroll
                for (int nb = 0; nb < 2; nb++)
                    Wx1[(size_t)row * HID + n0 + wn * 32 + nb * 16 + fr] = acc[mb][nb][r];
                float ve = acc[mb][0][r] * as0 + acc[mb][1][r] * as1;
                float vt = acc[mb][0][r] * at0 + acc[mb][1][r] * at1;
#pragma unroll
                for (int msk = 1; msk < 16; msk <<= 1) {
                    ve += __shfl_xor(ve, msk, 64);
                    vt += __shfl_xor(vt, msk, 64);
                }
                if (fr == 0) {
                    sm.g.esP[wm][wn][mb * 16 + kg * 4 + r] = ve;
                    sm.g.etP[wm][wn][mb * 16 + kg * 4 + r] = vt;
                }
            }
        }
        __syncthreads();
        if (t < 64) {
            int wmm = t >> 5, ri = t & 31;
            es1[h * NND + m0 + t] = sm.g.esP[wmm][0][ri] + sm.g.esP[wmm][1][ri];
            et1[h * NND + m0 + t] = sm.g.etP[wmm][0][ri] + sm.g.etP[wmm][1][ri];
        }
    } else if (bid < 1280) {
        int j = (bid - 256) * 256 + t;
        int n = j >> 8, k = j & 255;
        float v = W2[(size_t)k * C2 + n];
        unsigned short hi = f2bf(v);
        W2h[j] = hi; W2l[j] = f2bf(v - bf2f(hi));
    } else {
        int g = (bid - 1280) * 4 + (t >> 6);
        int lane = t & 63;
        int k = g & 255, hs = g >> 8, h = hs >> 1, sel = hs & 1;
        float acc = 0.f;
#pragma unroll
        for (int qq = 0; qq < 4; qq++)
            acc += W2[(size_t)k * C2 + h * 256 + qq * 64 + lane] *
                   attn2[h * 512 + sel * 256 + qq * 64 + lane];
        acc = wave_sum(acc);
        if (lane == 0) {
            if (sel) w_et[h * 256 + k] = acc;
            else     w_es[h * 256 + k] = acc;
        }
    }
}

// ---------------- k2: sort (generic) ----------------
__global__ __launch_bounds__(256) void k2_sort(const float* __restrict__ et,
        float* __restrict__ ts, int* __restrict__ perm) {
    __shared__ SMem sm;
    const int bid = blockIdx.x, t = threadIdx.x;
    sort_block(sm, et, ts, perm, bid >> 6, (bid & 63) * 64, t);
}

// ---------------- k3: layer-1 scan p1 (4h x 64d) + wprep1 ----------------
__global__ __launch_bounds__(256) void k3_scan1_p1(const float* __restrict__ Wx1,
        const float* __restrict__ ts1, const int* __restrict__ perm1,
        float* __restrict__ cTA, float* __restrict__ cTB,
        float* __restrict__ SA, float* __restrict__ SB) {
    __shared__ float swA[4], swB[4];
    const int bid = blockIdx.x, t = threadIdx.x;
    if (bid >= CH) { wprep_block(ts1, SA, SB, bid - CH, t, swA, swB); return; }
    const int h = t >> 6, d = t & 63;
    const int k0 = bid * CHR;
    const float tmax = ts1[h * NND + NND - 1];
    float aA = 0.f, aB = 0.f;
#pragma unroll
    for (int r = 0; r < CHR; r++) {
        float u = ts1[h * NND + k0 + r] - tmax;
        float wa = expf(u), wb = expf(LEAKY * u);
        int j = perm1[h * NND + k0 + r];
        float v = Wx1[(size_t)j * HID + h * D1 + d];
        aA += wa * v; aB += wb * v;
    }
    cTA[(h * CH + bid) * D1 + d] = aA;
    cTB[(h * CH + bid) * D1 + d] = aB;
}

// ---------------- p2: exclusive-scan chunk totals (in place) + totals ----------------
__global__ __launch_bounds__(256) void k_scan_p2(float* __restrict__ cTA,
        float* __restrict__ cTB, float* __restrict__ TotA, float* __restrict__ TotB,
        int D) {
    int h, d;
    if (D == D1) { h = threadIdx.x >> 6; d = threadIdx.x & 63; }
    else { h = blockIdx.x; d = threadIdx.x; }
    float rA = 0.f, rB = 0.f;
#pragma unroll 8
    for (int c = 0; c < CH; c++) {
        int o = (h * CH + c) * D + d;
        float vA = cTA[o], vB = cTB[o];
        cTA[o] = rA; cTB[o] = rB;
        rA += vA; rB += vB;
    }
    TotA[h * D + d] = rA;
    TotB[h * D + d] = rB;
}

// ---------------- k5: layer-1 scan p3 ----------------
__global__ __launch_bounds__(256) void k5_scan1_p3(const float* __restrict__ Wx1,
        const float* __restrict__ ts1, const int* __restrict__ perm1,
        const float* __restrict__ cTA, const float* __restrict__ cTB,
        const float* __restrict__ TotA,
        float* __restrict__ A, float* __restrict__ B) {
    const int ch = blockIdx.x, t = threadIdx.x;
    const int h = t >> 6, d = t & 63;
    const float tmax = ts1[h * NND + NND - 1];
    float runA = cTA[(h * CH + ch) * D1 + d];
    float runB = cTB[(h * CH + ch) * D1 + d];
    const float totA = TotA[h * D1 + d];
    const int k0 = ch * CHR;
    float v[CHR], wa[CHR], wb[CHR];
#pragma unroll
    for (int r = 0; r < CHR; r++) {
        float u = ts1[h * NND + k0 + r] - tmax;
        wa[r] = expf(u); wb[r] = expf(LEAKY * u);
        int j = perm1[h * NND + k0 + r];
        v[r] = Wx1[(size_t)j * HID + h * D1 + d];
    }
#pragma unroll
    for (int r = 0; r < CHR; r++) {
        size_t o = ((size_t)(h * NP1 + k0 + r)) * D1 + d;
        A[o] = totA - runA;
        B[o] = runB;
        runA += wa[r] * v[r];
        runB += wb[r] * v[r];
    }
    if (ch == CH - 1) {
        size_t o = ((size_t)(h * NP1 + NND)) * D1 + d;
        A[o] = totA - runA;
        B[o] = runB;
    }
}

// ---------------- k6: lookup1 -> h1 (split bf16) + fused escore2 ----------------
__global__ __launch_bounds__(256) void k6_lookup1(const float* __restrict__ es,
        const float* __restrict__ ts,
        const float* __restrict__ A, const float* __restrict__ Bv,
        const float* __restrict__ SA, const float* __restrict__ SB,
        const float* __restrict__ w_es, const float* __restrict__ w_et,
        unsigned short* __restrict__ h1h, unsigned short* __restrict__ h1l,
        float* __restrict__ es2, float* __restrict__ et2) {
    __shared__ float red2[4][8];
    const int i = blockIdx.x, t = threadIdx.x;
    const int h = t >> 6, d = t & 63;
    const int lane = t & 63, wid = t >> 6;
    float c = es[h * NND + i];
    float tmax = ts[h * NND + NND - 1];
    float s = c + tmax;
    float m = (s >= 0.f) ? s : LEAKY * s;
    float al = expf(s - m);
    float be = expf(LEAKY * s - m);
    int k = lower_bound_f(ts + h * NND, -c);
    size_t o = ((size_t)(h * NP1 + k)) * D1 + d;
    float num = al * A[o] + be * Bv[o];
    float den = al * SA[h * NP1 + k] + be * SB[h * NP1 + k];
    float val = num / den;
    float hv = (val > 0.f) ? val : expm1f(val);
    unsigned short hh = f2bf(hv);
    h1h[i * HID + t] = hh;
    h1l[i * HID + t] = f2bf(hv - bf2f(hh));
#pragma unroll
    for (int oo = 0; oo < 8; oo++) {
        int hhh = oo >> 1;
        const float* wv = (oo & 1) ? w_et : w_es;
        float p = hv * wv[hhh * HID + t];
        p = wave_sum(p);
        if (lane == 0) red2[wid][oo] = p;
    }
    __syncthreads();
    if (t < 8) {
        float sv = red2[0][t] + red2[1][t] + red2[2][t] + red2[3][t];
        int hhh = t >> 1;
        if (t & 1) et2[hhh * NND + i] = sv;
        else       es2[hhh * NND + i] = sv;
    }
}

// ---------------- k7: gemm2 (pre-split A,B) | sort2 ----------------
__global__ __launch_bounds__(256) void k7_gemm2_sort2(
        const unsigned short* __restrict__ h1h, const unsigned short* __restrict__ h1l,
        const unsigned short* __restrict__ W2h, const unsigned short* __restrict__ W2l,
        float* __restrict__ Wx2,
        const float* __restrict__ et2, float* __restrict__ ts2, int* __restrict__ perm2) {
    __shared__ SMem sm;
    const int bid = blockIdx.x, t = threadIdx.x;
    if (bid >= 1024) {
        sort_block(sm, et2, ts2, perm2, (bid - 1024) >> 6, ((bid - 1024) & 63) * 64, t);
        return;
    }
    const int lane = t & 63, w = t >> 6;
    const int wm = w >> 1, wn = w & 1;
    const int n0 = (bid & 15) * 64, m0 = (bid >> 4) * 64;
    const int fr = lane & 15, kg = lane >> 4;
    f32x4 z4 = {0.f, 0.f, 0.f, 0.f};
    f32x4 acc[2][2] = {{z4, z4}, {z4, z4}};
    for (int k0 = 0; k0 < HID; k0 += 32) {
        {
            int r = t >> 2, kq = (t & 3) * 8;
            *(u16x8*)&sm.g.Ah[r][kq] = *(const u16x8*)&h1h[(size_t)(m0 + r) * HID + k0 + kq];
            *(u16x8*)&sm.g.Al[r][kq] = *(const u16x8*)&h1l[(size_t)(m0 + r) * HID + k0 + kq];
            *(u16x8*)&sm.g.Bh[r][kq] = *(const u16x8*)&W2h[(size_t)(n0 + r) * HID + k0 + kq];
            *(u16x8*)&sm.g.Bl[r][kq] = *(const u16x8*)&W2l[(size_t)(n0 + r) * HID + k0 + kq];
        }
        __syncthreads();
        bf16x8 ah0 = *(bf16x8*)&sm.g.Ah[wm * 32 + fr][kg * 8];
        bf16x8 ah1 = *(bf16x8*)&sm.g.Ah[wm * 32 + 16 + fr][kg * 8];
        bf16x8 al0 = *(bf16x8*)&sm.g.Al[wm * 32 + fr][kg * 8];
        bf16x8 al1 = *(bf16x8*)&sm.g.Al[wm * 32 + 16 + fr][kg * 8];
        bf16x8 bh0 = *(bf16x8*)&sm.g.Bh[wn * 32 + fr][kg * 8];
        bf16x8 bh1 = *(bf16x8*)&sm.g.Bh[wn * 32 + 16 + fr][kg * 8];
        bf16x8 bl0 = *(bf16x8*)&sm.g.Bl[wn * 32 + fr][kg * 8];
        bf16x8 bl1 = *(bf16x8*)&sm.g.Bl[wn * 32 + 16 + fr][kg * 8];
        MM(ah0, bh0, acc[0][0]); MM(ah0, bl0, acc[0][0]); MM(al0, bh0, acc[0][0]);
        MM(ah0, bh1, acc[0][1]); MM(ah0, bl1, acc[0][1]); MM(al0, bh1, acc[0][1]);
        MM(ah1, bh0, acc[1][0]); MM(ah1, bl0, acc[1][0]); MM(al1, bh0, acc[1][0]);
        MM(ah1, bh1, acc[1][1]); MM(ah1, bl1, acc[1][1]); MM(al1, bh1, acc[1][1]);
        __syncthreads();
    }
#pragma unroll
    for (int mb = 0; mb < 2; mb++)
#pragma unroll
        for (int r = 0; r < 4; r++) {
            int row = m0 + wm * 32 + mb * 16 + kg * 4 + r;
#pragma unroll
            for (int nb = 0; nb < 2; nb++)
                Wx2[(size_t)row * C2 + n0 + wn * 32 + nb * 16 + fr] = acc[mb][nb][r];
        }
}

// ---------------- k8: layer-2 scan p1 + wprep2 ----------------
__global__ __launch_bounds__(256) void k8_scan2_p1(const float* __restrict__ Wx2,
        const float* __restrict__ ts2, const int* __restrict__ perm2,
        float* __restrict__ cTA, float* __restrict__ cTB,
        float* __restrict__ SA, float* __restrict__ SB) {
    __shared__ float swA[4], swB[4];
    const int bid = blockIdx.x, t = threadIdx.x;
    if (bid >= 2048) { wprep_block(ts2, SA, SB, bid - 2048, t, swA, swB); return; }
    const int ch = bid & (CH - 1), h = bid >> 9;
    const int d = t, k0 = ch * CHR;
    const float tmax = ts2[h * NND + NND - 1];
    float aA = 0.f, aB = 0.f;
#pragma unroll
    for (int r = 0; r < CHR; r++) {
        float u = ts2[h * NND + k0 + r] - tmax;
        float wa = expf(u), wb = expf(LEAKY * u);
        int j = perm2[h * NND + k0 + r];
        float v = Wx2[(size_t)j * C2 + h * D2 + d];
        aA += wa * v; aB += wb * v;
    }
    cTA[(h * CH + ch) * D2 + d] = aA;
    cTB[(h * CH + ch) * D2 + d] = aB;
}

// ---------------- k10: layer-2 scan p3 ----------------
__global__ __launch_bounds__(256) void k10_scan2_p3(const float* __restrict__ Wx2,
        const float* __restrict__ ts2, const int* __restrict__ perm2,
        const float* __restrict__ cTA, const float* __restrict__ cTB,
        const float* __restrict__ TotA,
        float* __restrict__ A, float* __restrict__ B) {
    const int bid = blockIdx.x, t = threadIdx.x;
    const int ch = bid & (CH - 1), h = bid >> 9;
    const int d = t;
    const float tmax = ts2[h * NND + NND - 1];
    float runA = cTA[(h * CH + ch) * D2 + d];
    float runB = cTB[(h * CH + ch) * D2 + d];
    const float totA = TotA[h * D2 + d];
    const int k0 = ch * CHR;
    float v[CHR], wa[CHR], wb[CHR];
#pragma unroll
    for (int r = 0; r < CHR; r++) {
        float u = ts2[h * NND + k0 + r] - tmax;
        wa[r] = expf(u); wb[r] = expf(LEAKY * u);
        int j = perm2[h * NND + k0 + r];
        v[r] = Wx2[(size_t)j * C2 + h * D2 + d];
    }
#pragma unroll
    for (int r = 0; r < CHR; r++) {
        size_t o = ((size_t)(h * NP1 + k0 + r)) * D2 + d;
        A[o] = totA - runA;
        B[o] = runB;
        runA += wa[r] * v[r];
        runB += wb[r] * v[r];
    }
    if (ch == CH - 1) {
        size_t o = ((size_t)(h * NP1 + NND)) * D2 + d;
        A[o] = totA - runA;
        B[o] = runB;
    }
}

// ---------------- k11: lookup2 (head-mean + ELU + LayerNorm) ----------------
__global__ __launch_bounds__(256) void k11_lookup2(const float* __restrict__ es,
        const float* __restrict__ ts,
        const float* __restrict__ A, const float* __restrict__ B,
        const float* __restrict__ SA, const float* __restrict__ SB,
        const float* __restrict__ gamma, const float* __restrict__ betap,
        float* __restrict__ out) {
    __shared__ float red[4];
    const int i = blockIdx.x;
    const int t = threadIdx.x;
    const int wid = t >> 6, lane = t & 63;
    float acc = 0.f;
#pragma unroll
    for (int h = 0; h < HEADS; h++) {
        float c = es[h * NND + i];
        float tmax = ts[h * NND + NND - 1];
        float s = c + tmax;
        float m = (s >= 0.f) ? s : LEAKY * s;
        float al = expf(s - m);
        float be = expf(LEAKY * s - m);
        int k = lower_bound_f(ts + h * NND, -c);
        size_t o = ((size_t)(h * NP1 + k)) * D2 + t;
        float num = al * A[o] + be * B[o];
        float den = al * SA[h * NP1 + k] + be * SB[h * NP1 + k];
        acc += num / den;
    }
    acc *= 0.25f;
    float xv = (acc > 0.f) ? acc : expm1f(acc);
    float sv = wave_sum(xv);
    if (lane == 0) red[wid] = sv;
    __syncthreads();
    float mu = (red[0] + red[1] + red[2] + red[3]) * (1.f / 256.f);
    __syncthreads();
    float dv = xv - mu;
    float s2 = wave_sum(dv * dv);
    if (lane == 0) red[wid] = s2;
    __syncthreads();
    float var = (red[0] + red[1] + red[2] + red[3]) * (1.f / 256.f);
    out[i * D2 + t] = gamma[t] * dv * rsqrtf(var + LN_EPS) + betap[t];
}

extern "C" void kernel_launch(void* const* d_in, const int* in_sizes, int n_in,
                              void* d_out, int out_size, void* d_ws, size_t ws_size,
                              hipStream_t stream) {
    const float* x     = (const float*)d_in[0];
    const float* W1    = (const float*)d_in[1];
    const float* attn1 = (const float*)d_in[2];
    const float* W2    = (const float*)d_in[3];
    const float* attn2 = (const float*)d_in[4];
    const float* gamma = (const float*)d_in[5];
    const float* betap = (const float*)d_in[6];
    float* out = (float*)d_out;

    char* ws = (char*)d_ws;
    size_t off = 0;
    auto alloc = [&](size_t nbytes) -> void* {
        void* p = (void*)(ws + off);
        off += (nbytes + 255) & ~(size_t)255;
        return p;
    };

    float* Wx1 = (float*)alloc((size_t)NND * HID * 4);
    float* Wx2 = (float*)alloc((size_t)NND * C2 * 4);
    unsigned short* h1h = (unsigned short*)alloc((size_t)NND * HID * 2);
    unsigned short* h1l = (unsigned short*)alloc((size_t)NND * HID * 2);
    float* es1 = (float*)alloc((size_t)HEADS * NND * 4);
    float* et1 = (float*)alloc((size_t)HEADS * NND * 4);
    float* es2 = (float*)alloc((size_t)HEADS * NND * 4);
    float* et2 = (float*)alloc((size_t)HEADS * NND * 4);
    float* ts1 = (float*)alloc((size_t)HEADS * NND * 4);
    float* ts2 = (float*)alloc((size_t)HEADS * NND * 4);
    int* perm1 = (int*)alloc((size_t)HEADS * NND * 4);
    int* perm2 = (int*)alloc((size_t)HEADS * NND * 4);
    float* A   = (float*)alloc((size_t)HEADS * NP1 * D2 * 4);
    float* B   = (float*)alloc((size_t)HEADS * NP1 * D2 * 4);
    float* SA  = (float*)alloc((size_t)HEADS * NP1 * 4);
    float* SB  = (float*)alloc((size_t)HEADS * NP1 * 4);
    float* cTA = (float*)alloc((size_t)HEADS * CH * D2 * 4);
    float* cTB = (float*)alloc((size_t)HEADS * CH * D2 * 4);
    float* TotA = (float*)alloc((size_t)HEADS * D2 * 4);
    float* TotB = (float*)alloc((size_t)HEADS * D2 * 4);
    unsigned short* W2h = (unsigned short*)alloc((size_t)262144 * 2);
    unsigned short* W2l = (unsigned short*)alloc((size_t)262144 * 2);
    float* w_es = (float*)alloc((size_t)HEADS * HID * 4);
    float* w_et = (float*)alloc((size_t)HEADS * HID * 4);
    (void)ws_size; (void)in_sizes; (void)n_in; (void)out_size;

    // ---- layer 1 ----
    k1_gemm1_prep<<<1792, 256, 0, stream>>>(x, W1, attn1, W2, attn2,
                                            Wx1, es1, et1, W2h, W2l, w_es, w_et);
    k2_sort<<<256, 256, 0, stream>>>(et1, ts1, perm1);
    k3_scan1_p1<<<CH + 4, 256, 0, stream>>>(Wx1, ts1, perm1, cTA, cTB, SA, SB);
    k_scan_p2<<<1, 256, 0, stream>>>(cTA, cTB, TotA, TotB, D1);
    k5_scan1_p3<<<CH, 256, 0, stream>>>(Wx1, ts1, perm1, cTA, cTB, TotA, A, B);
    k6_lookup1<<<NND, 256, 0, stream>>>(es1, ts1, A, B, SA, SB, w_es, w_et,
                                        h1h, h1l, es2, et2);

    // ---- layer 2 ----
    k7_gemm2_sort2<<<1280, 256, 0, stream>>>(h1h, h1l, W2h, W2l, Wx2, et2, ts2, perm2);
    k8_scan2_p1<<<2052, 256, 0, stream>>>(Wx2, ts2, perm2, cTA, cTB, SA, SB);
    k_scan_p2<<<4, 256, 0, stream>>>(cTA, cTB, TotA, TotB, D2);
    k10_scan2_p3<<<2048, 256, 0, stream>>>(Wx2, ts2, perm2, cTA, cTB, TotA, A, B);
    k11_lookup2<<<NND, 256, 0, stream>>>(es2, ts2, A, B, SA, SB, gamma, betap, out);
}

// Round 7
// 191.143 us; speedup vs baseline: 5.8097x; 1.7064x over previous
//
#include <hip/hip_runtime.h>
#include <math.h>

#define NND 4096
#define SDIM 128
#define HEADS 4
#define D1 64
#define HID 256
#define D2 256
#define C2 1024
#define NP1 (NND + 1)
#define CH 512
#define CHR 8
#define LEAKY 0.2f
#define LN_EPS 1e-5f
#define LDA 40

typedef __attribute__((ext_vector_type(8))) short bf16x8;
typedef __attribute__((ext_vector_type(4))) float f32x4;
typedef __attribute__((ext_vector_type(8))) unsigned short u16x8;
typedef __attribute__((ext_vector_type(4))) unsigned short u16x4;

union SMem {
    struct {
        unsigned short Ah[64][LDA], Al[64][LDA], Bh[64][LDA], Bl[64][LDA];
        float esP[2][2][32], etP[2][2][32];
    } g;
    struct { unsigned key[NND]; int pr[64]; } s;
};

__device__ __forceinline__ unsigned short f2bf(float f) {
    union { float f; unsigned u; } v; v.f = f;
    unsigned r = v.u + 0x7FFFu + ((v.u >> 16) & 1u);
    return (unsigned short)(r >> 16);
}
__device__ __forceinline__ float bf2f(unsigned short s) {
    union { unsigned u; float f; } v; v.u = ((unsigned)s) << 16; return v.f;
}
__device__ __forceinline__ float wave_sum(float v) {
#pragma unroll
    for (int o = 32; o > 0; o >>= 1) v += __shfl_xor(v, o, 64);
    return v;
}
__device__ __forceinline__ int lower_bound_f(const float* __restrict__ a, float x) {
    int lo = 0, hi = NND;
    while (lo < hi) {
        int mid = (lo + hi) >> 1;
        if (a[mid] < x) lo = mid + 1; else hi = mid;
    }
    return lo;
}

#define MM(a, b, c) c = __builtin_amdgcn_mfma_f32_16x16x32_bf16(a, b, c, 0, 0, 0)

// ---------------- sort: rank of 64 elems/block vs all keys (sortable uint) ----------------
__device__ __forceinline__ void sort_block(SMem& sm, const float* __restrict__ et,
        float* __restrict__ ts, int* __restrict__ perm, int h, int e0, int t) {
    for (int p = t; p < NND; p += 256) {
        unsigned u = __float_as_uint(et[h * NND + p]);
        sm.s.key[p] = (u & 0x80000000u) ? ~u : (u | 0x80000000u);
    }
    if (t < 64) sm.s.pr[t] = 0;
    __syncthreads();
    const int e = t & 63, sg = t >> 6;
    const int myIdx = e0 + e;
    const unsigned myU = sm.s.key[myIdx];
    int rank = 0;
    const int kbeg = sg * (NND / 4);
#pragma unroll 8
    for (int k = kbeg; k < kbeg + NND / 4; k++) {
        unsigned v = sm.s.key[k];
        rank += (v < myU || (v == myU && k < myIdx)) ? 1 : 0;
    }
    atomicAdd(&sm.s.pr[e], rank);
    __syncthreads();
    if (t < 64) {
        int r = sm.s.pr[t];
        unsigned u = sm.s.key[e0 + t];
        float f = (u & 0x80000000u) ? __uint_as_float(u ^ 0x80000000u)
                                    : __uint_as_float(~u);
        ts[h * NND + r] = f;
        perm[h * NND + r] = e0 + t;
    }
}

// ---------------- per-head scalar weight scan: SA (suffix incl), SB (prefix excl) --------
__device__ __forceinline__ void wprep_block(const float* __restrict__ ts,
        float* __restrict__ SA, float* __restrict__ SB, int h, int t,
        float* swA, float* swB) {
    const int lane = t & 63, w = t >> 6;
    const float tmax = ts[h * NND + NND - 1];
    float a[16], b[16];
    float la = 0.f, lb = 0.f;
    const int kb = t * 16;
#pragma unroll
    for (int q = 0; q < 16; q++) {
        float u = ts[h * NND + kb + q] - tmax;
        a[q] = expf(u); b[q] = expf(LEAKY * u);
        la += a[q]; lb += b[q];
    }
    float sa = la, sb = lb;
#pragma unroll
    for (int o = 1; o < 64; o <<= 1) {
        float ua = __shfl_up(sa, o, 64);
        float ub = __shfl_up(sb, o, 64);
        if (lane >= o) { sa += ua; sb += ub; }
    }
    if (lane == 63) { swA[w] = sa; swB[w] = sb; }
    __syncthreads();
    float baseA = 0.f, baseB = 0.f, totA = 0.f, totB = 0.f;
#pragma unroll
    for (int ww = 0; ww < 4; ww++) {
        float va = swA[ww], vb = swB[ww];
        totA += va; totB += vb;
        if (ww < w) { baseA += va; baseB += vb; }
    }
    float preA = baseA + sa - la;
    float preB = baseB + sb - lb;
#pragma unroll
    for (int q = 0; q < 16; q++) {
        SA[h * NP1 + kb + q] = totA - preA;
        SB[h * NP1 + kb + q] = preB;
        preA += a[q]; preB += b[q];
    }
    if (t == 255) { SA[h * NP1 + NND] = 0.f; SB[h * NP1 + NND] = totB; }
}

// ---------------- k1: gemm1 (inline W1 split, fused escore1) | W2 prep | attn2 fold ------
__global__ __launch_bounds__(256) void k1_gemm1_prep(
        const float* __restrict__ x, const float* __restrict__ W1,
        const float* __restrict__ attn1,
        const float* __restrict__ W2, const float* __restrict__ attn2,
        float* __restrict__ Wx1, float* __restrict__ es1, float* __restrict__ et1,
        unsigned short* __restrict__ W2h, unsigned short* __restrict__ W2l,
        float* __restrict__ w_es, float* __restrict__ w_et) {
    __shared__ SMem sm;
    const int bid = blockIdx.x, t = threadIdx.x;
    if (bid < 256) {
        const int lane = t & 63, w = t >> 6;
        const int wm = w >> 1, wn = w & 1;
        const int h = bid & 3, n0 = h * 64, m0 = (bid >> 2) * 64;
        const int fr = lane & 15, kg = lane >> 4;
        f32x4 z4 = {0.f, 0.f, 0.f, 0.f};
        f32x4 acc[2][2] = {{z4, z4}, {z4, z4}};
        for (int k0 = 0; k0 < SDIM; k0 += 32) {
#pragma unroll
            for (int q = 0; q < 2; q++) {
                int p = t + 256 * q, r = p >> 3, kk = (p & 7) * 4;
                float4 av = *(const float4*)&x[(size_t)(m0 + r) * SDIM + k0 + kk];
                float fv[4] = {av.x, av.y, av.z, av.w};
                unsigned short hi4[4], lo4[4];
#pragma unroll
                for (int i = 0; i < 4; i++) {
                    hi4[i] = f2bf(fv[i]);
                    lo4[i] = f2bf(fv[i] - bf2f(hi4[i]));
                }
                *(u16x4*)&sm.g.Ah[r][kk] = (u16x4){hi4[0], hi4[1], hi4[2], hi4[3]};
                *(u16x4*)&sm.g.Al[r][kk] = (u16x4){lo4[0], lo4[1], lo4[2], lo4[3]};
            }
            {
                const int kq4 = t >> 6;
                unsigned short bh[8], bl[8];
#pragma unroll
                for (int i = 0; i < 8; i++) {
                    float v = W1[(size_t)(k0 + kq4 * 8 + i) * HID + n0 + lane];
                    bh[i] = f2bf(v);
                    bl[i] = f2bf(v - bf2f(bh[i]));
                }
                u16x8 ph, pl;
#pragma unroll
                for (int i = 0; i < 8; i++) { ph[i] = bh[i]; pl[i] = bl[i]; }
                *(u16x8*)&sm.g.Bh[lane][kq4 * 8] = ph;
                *(u16x8*)&sm.g.Bl[lane][kq4 * 8] = pl;
            }
            __syncthreads();
            bf16x8 ah0 = *(bf16x8*)&sm.g.Ah[wm * 32 + fr][kg * 8];
            bf16x8 ah1 = *(bf16x8*)&sm.g.Ah[wm * 32 + 16 + fr][kg * 8];
            bf16x8 al0 = *(bf16x8*)&sm.g.Al[wm * 32 + fr][kg * 8];
            bf16x8 al1 = *(bf16x8*)&sm.g.Al[wm * 32 + 16 + fr][kg * 8];
            bf16x8 bh0 = *(bf16x8*)&sm.g.Bh[wn * 32 + fr][kg * 8];
            bf16x8 bh1 = *(bf16x8*)&sm.g.Bh[wn * 32 + 16 + fr][kg * 8];
            bf16x8 bl0 = *(bf16x8*)&sm.g.Bl[wn * 32 + fr][kg * 8];
            bf16x8 bl1 = *(bf16x8*)&sm.g.Bl[wn * 32 + 16 + fr][kg * 8];
            MM(ah0, bh0, acc[0][0]); MM(ah0, bl0, acc[0][0]); MM(al0, bh0, acc[0][0]);
            MM(ah0, bh1, acc[0][1]); MM(ah0, bl1, acc[0][1]); MM(al0, bh1, acc[0][1]);
            MM(ah1, bh0, acc[1][0]); MM(ah1, bl0, acc[1][0]); MM(al1, bh0, acc[1][0]);
            MM(ah1, bh1, acc[1][1]); MM(ah1, bl1, acc[1][1]); MM(al1, bh1, acc[1][1]);
            __syncthreads();
        }
        const float as0 = attn1[h * 128 + wn * 32 + fr];
        const float as1 = attn1[h * 128 + wn * 32 + 16 + fr];
        const float at0 = attn1[h * 128 + 64 + wn * 32 + fr];
        const float at1 = attn1[h * 128 + 64 + wn * 32 + 16 + fr];
#pragma unroll
        for (int mb = 0; mb < 2; mb++) {
#pragma unroll
            for (int r = 0; r < 4; r++) {
                int row = m0 + wm * 32 + mb * 16 + kg * 4 + r;
#pragma unroll
                for (int nb = 0; nb < 2; nb++)
                    Wx1[(size_t)row * HID + n0 + wn * 32 + nb * 16 + fr] = acc[mb][nb][r];
                float ve = acc[mb][0][r] * as0 + acc[mb][1][r] * as1;
                float vt = acc[mb][0][r] * at0 + acc[mb][1][r] * at1;
#pragma unroll
                for (int msk = 1; msk < 16; msk <<= 1) {
                    ve += __shfl_xor(ve, msk, 64);
                    vt += __shfl_xor(vt, msk, 64);
                }
                if (fr == 0) {
                    sm.g.esP[wm][wn][mb * 16 + kg * 4 + r] = ve;
                    sm.g.etP[wm][wn][mb * 16 + kg * 4 + r] = vt;
                }
            }
        }
        __syncthreads();
        if (t < 64) {
            int wmm = t >> 5, ri = t & 31;
            es1[h * NND + m0 + t] = sm.g.esP[wmm][0][ri] + sm.g.esP[wmm][1][ri];
            et1[h * NND + m0 + t] = sm.g.etP[wmm][0][ri] + sm.g.etP[wmm][1][ri];
        }
    } else if (bid < 1280) {
        int j = (bid - 256) * 256 + t;
        int n = j >> 8, k = j & 255;
        float v = W2[(size_t)k * C2 + n];
        unsigned short hi = f2bf(v);
        W2h[j] = hi; W2l[j] = f2bf(v - bf2f(hi));
    } else {
        int g = (bid - 1280) * 4 + (t >> 6);
        int lane = t & 63;
        int k = g & 255, hs = g >> 8, h = hs >> 1, sel = hs & 1;
        float acc = 0.f;
#pragma unroll
        for (int qq = 0; qq < 4; qq++)
            acc += W2[(size_t)k * C2 + h * 256 + qq * 64 + lane] *
                   attn2[h * 512 + sel * 256 + qq * 64 + lane];
        acc = wave_sum(acc);
        if (lane == 0) {
            if (sel) w_et[h * 256 + k] = acc;
            else     w_es[h * 256 + k] = acc;
        }
    }
}

// ---------------- k2: sort (generic) ----------------
__global__ __launch_bounds__(256) void k2_sort(const float* __restrict__ et,
        float* __restrict__ ts, int* __restrict__ perm) {
    __shared__ SMem sm;
    const int bid = blockIdx.x, t = threadIdx.x;
    sort_block(sm, et, ts, perm, bid >> 6, (bid & 63) * 64, t);
}

// ---------------- k3: layer-1 scan p1 (4h x 64d) + wprep1 ----------------
__global__ __launch_bounds__(256) void k3_scan1_p1(const float* __restrict__ Wx1,
        const float* __restrict__ ts1, const int* __restrict__ perm1,
        float* __restrict__ cTA, float* __restrict__ cTB,
        float* __restrict__ SA, float* __restrict__ SB) {
    __shared__ float swA[4], swB[4];
    const int bid = blockIdx.x, t = threadIdx.x;
    if (bid >= CH) { wprep_block(ts1, SA, SB, bid - CH, t, swA, swB); return; }
    const int h = t >> 6, d = t & 63;
    const int k0 = bid * CHR;
    const float tmax = ts1[h * NND + NND - 1];
    float aA = 0.f, aB = 0.f;
#pragma unroll
    for (int r = 0; r < CHR; r++) {
        float u = ts1[h * NND + k0 + r] - tmax;
        float wa = expf(u), wb = expf(LEAKY * u);
        int j = perm1[h * NND + k0 + r];
        float v = Wx1[(size_t)j * HID + h * D1 + d];
        aA += wa * v; aB += wb * v;
    }
    cTA[(h * CH + bid) * D1 + d] = aA;
    cTB[(h * CH + bid) * D1 + d] = aB;
}

// ---------------- p2: wave-parallel exclusive scan of chunk totals (in place) ------------
// One wave per (h,d) column; lane l holds chunks c = 8l..8l+7.
__global__ __launch_bounds__(256) void k_scan_p2(float* __restrict__ cTA,
        float* __restrict__ cTB, float* __restrict__ TotA, float* __restrict__ TotB,
        int logD) {
    const int t = threadIdx.x;
    const int lane = t & 63, w = t >> 6;
    const int D = 1 << logD;
    const int col = blockIdx.x * 4 + w;        // 0 .. HEADS*D-1
    const int h = col >> logD, d = col & (D - 1);
    const size_t base = (size_t)h * CH * D + d;
    float vA[8], vB[8];
#pragma unroll
    for (int q = 0; q < 8; q++) {
        size_t o = base + (size_t)(lane * 8 + q) * D;
        vA[q] = cTA[o];
        vB[q] = cTB[o];
    }
    // in-lane totals
    float laA = 0.f, laB = 0.f;
#pragma unroll
    for (int q = 0; q < 8; q++) { laA += vA[q]; laB += vB[q]; }
    // wave inclusive scan of lane totals
    float sA = laA, sB = laB;
#pragma unroll
    for (int o = 1; o < 64; o <<= 1) {
        float uA = __shfl_up(sA, o, 64);
        float uB = __shfl_up(sB, o, 64);
        if (lane >= o) { sA += uA; sB += uB; }
    }
    float totA = __shfl(sA, 63, 64);
    float totB = __shfl(sB, 63, 64);
    // exclusive prefix at this lane's first chunk
    float runA = sA - laA, runB = sB - laB;
#pragma unroll
    for (int q = 0; q < 8; q++) {
        size_t o = base + (size_t)(lane * 8 + q) * D;
        float tA = vA[q], tB = vB[q];
        cTA[o] = runA;
        cTB[o] = runB;
        runA += tA; runB += tB;
    }
    if (lane == 0) {
        TotA[h * D + d] = totA;
        TotB[h * D + d] = totB;
    }
}

// ---------------- k5: layer-1 scan p3 ----------------
__global__ __launch_bounds__(256) void k5_scan1_p3(const float* __restrict__ Wx1,
        const float* __restrict__ ts1, const int* __restrict__ perm1,
        const float* __restrict__ cTA, const float* __restrict__ cTB,
        const float* __restrict__ TotA,
        float* __restrict__ A, float* __restrict__ B) {
    const int ch = blockIdx.x, t = threadIdx.x;
    const int h = t >> 6, d = t & 63;
    const float tmax = ts1[h * NND + NND - 1];
    float runA = cTA[(h * CH + ch) * D1 + d];
    float runB = cTB[(h * CH + ch) * D1 + d];
    const float totA = TotA[h * D1 + d];
    const int k0 = ch * CHR;
    float v[CHR], wa[CHR], wb[CHR];
#pragma unroll
    for (int r = 0; r < CHR; r++) {
        float u = ts1[h * NND + k0 + r] - tmax;
        wa[r] = expf(u); wb[r] = expf(LEAKY * u);
        int j = perm1[h * NND + k0 + r];
        v[r] = Wx1[(size_t)j * HID + h * D1 + d];
    }
#pragma unroll
    for (int r = 0; r < CHR; r++) {
        size_t o = ((size_t)(h * NP1 + k0 + r)) * D1 + d;
        A[o] = totA - runA;
        B[o] = runB;
        runA += wa[r] * v[r];
        runB += wb[r] * v[r];
    }
    if (ch == CH - 1) {
        size_t o = ((size_t)(h * NP1 + NND)) * D1 + d;
        A[o] = totA - runA;
        B[o] = runB;
    }
}

// ---------------- k6: lookup1 -> h1 (split bf16) + fused escore2 ----------------
__global__ __launch_bounds__(256) void k6_lookup1(const float* __restrict__ es,
        const float* __restrict__ ts,
        const float* __restrict__ A, const float* __restrict__ Bv,
        const float* __restrict__ SA, const float* __restrict__ SB,
        const float* __restrict__ w_es, const float* __restrict__ w_et,
        unsigned short* __restrict__ h1h, unsigned short* __restrict__ h1l,
        float* __restrict__ es2, float* __restrict__ et2) {
    __shared__ float red2[4][8];
    const int i = blockIdx.x, t = threadIdx.x;
    const int h = t >> 6, d = t & 63;
    const int lane = t & 63, wid = t >> 6;
    float c = es[h * NND + i];
    float tmax = ts[h * NND + NND - 1];
    float s = c + tmax;
    float m = (s >= 0.f) ? s : LEAKY * s;
    float al = expf(s - m);
    float be = expf(LEAKY * s - m);
    int k = lower_bound_f(ts + h * NND, -c);
    size_t o = ((size_t)(h * NP1 + k)) * D1 + d;
    float num = al * A[o] + be * Bv[o];
    float den = al * SA[h * NP1 + k] + be * SB[h * NP1 + k];
    float val = num / den;
    float hv = (val > 0.f) ? val : expm1f(val);
    unsigned short hh = f2bf(hv);
    h1h[i * HID + t] = hh;
    h1l[i * HID + t] = f2bf(hv - bf2f(hh));
#pragma unroll
    for (int oo = 0; oo < 8; oo++) {
        int hhh = oo >> 1;
        const float* wv = (oo & 1) ? w_et : w_es;
        float p = hv * wv[hhh * HID + t];
        p = wave_sum(p);
        if (lane == 0) red2[wid][oo] = p;
    }
    __syncthreads();
    if (t < 8) {
        float sv = red2[0][t] + red2[1][t] + red2[2][t] + red2[3][t];
        int hhh = t >> 1;
        if (t & 1) et2[hhh * NND + i] = sv;
        else       es2[hhh * NND + i] = sv;
    }
}

// ---------------- k7: gemm2 (pre-split A,B) | sort2 ----------------
__global__ __launch_bounds__(256) void k7_gemm2_sort2(
        const unsigned short* __restrict__ h1h, const unsigned short* __restrict__ h1l,
        const unsigned short* __restrict__ W2h, const unsigned short* __restrict__ W2l,
        float* __restrict__ Wx2,
        const float* __restrict__ et2, float* __restrict__ ts2, int* __restrict__ perm2) {
    __shared__ SMem sm;
    const int bid = blockIdx.x, t = threadIdx.x;
    if (bid >= 1024) {
        sort_block(sm, et2, ts2, perm2, (bid - 1024) >> 6, ((bid - 1024) & 63) * 64, t);
        return;
    }
    const int lane = t & 63, w = t >> 6;
    const int wm = w >> 1, wn = w & 1;
    const int n0 = (bid & 15) * 64, m0 = (bid >> 4) * 64;
    const int fr = lane & 15, kg = lane >> 4;
    f32x4 z4 = {0.f, 0.f, 0.f, 0.f};
    f32x4 acc[2][2] = {{z4, z4}, {z4, z4}};
    for (int k0 = 0; k0 < HID; k0 += 32) {
        {
            int r = t >> 2, kq = (t & 3) * 8;
            *(u16x8*)&sm.g.Ah[r][kq] = *(const u16x8*)&h1h[(size_t)(m0 + r) * HID + k0 + kq];
            *(u16x8*)&sm.g.Al[r][kq] = *(const u16x8*)&h1l[(size_t)(m0 + r) * HID + k0 + kq];
            *(u16x8*)&sm.g.Bh[r][kq] = *(const u16x8*)&W2h[(size_t)(n0 + r) * HID + k0 + kq];
            *(u16x8*)&sm.g.Bl[r][kq] = *(const u16x8*)&W2l[(size_t)(n0 + r) * HID + k0 + kq];
        }
        __syncthreads();
        bf16x8 ah0 = *(bf16x8*)&sm.g.Ah[wm * 32 + fr][kg * 8];
        bf16x8 ah1 = *(bf16x8*)&sm.g.Ah[wm * 32 + 16 + fr][kg * 8];
        bf16x8 al0 = *(bf16x8*)&sm.g.Al[wm * 32 + fr][kg * 8];
        bf16x8 al1 = *(bf16x8*)&sm.g.Al[wm * 32 + 16 + fr][kg * 8];
        bf16x8 bh0 = *(bf16x8*)&sm.g.Bh[wn * 32 + fr][kg * 8];
        bf16x8 bh1 = *(bf16x8*)&sm.g.Bh[wn * 32 + 16 + fr][kg * 8];
        bf16x8 bl0 = *(bf16x8*)&sm.g.Bl[wn * 32 + fr][kg * 8];
        bf16x8 bl1 = *(bf16x8*)&sm.g.Bl[wn * 32 + 16 + fr][kg * 8];
        MM(ah0, bh0, acc[0][0]); MM(ah0, bl0, acc[0][0]); MM(al0, bh0, acc[0][0]);
        MM(ah0, bh1, acc[0][1]); MM(ah0, bl1, acc[0][1]); MM(al0, bh1, acc[0][1]);
        MM(ah1, bh0, acc[1][0]); MM(ah1, bl0, acc[1][0]); MM(al1, bh0, acc[1][0]);
        MM(ah1, bh1, acc[1][1]); MM(ah1, bl1, acc[1][1]); MM(al1, bh1, acc[1][1]);
        __syncthreads();
    }
#pragma unroll
    for (int mb = 0; mb < 2; mb++)
#pragma unroll
        for (int r = 0; r < 4; r++) {
            int row = m0 + wm * 32 + mb * 16 + kg * 4 + r;
#pragma unroll
            for (int nb = 0; nb < 2; nb++)
                Wx2[(size_t)row * C2 + n0 + wn * 32 + nb * 16 + fr] = acc[mb][nb][r];
        }
}

// ---------------- k8: layer-2 scan p1 + wprep2 ----------------
__global__ __launch_bounds__(256) void k8_scan2_p1(const float* __restrict__ Wx2,
        const float* __restrict__ ts2, const int* __restrict__ perm2,
        float* __restrict__ cTA, float* __restrict__ cTB,
        float* __restrict__ SA, float* __restrict__ SB) {
    __shared__ float swA[4], swB[4];
    const int bid = blockIdx.x, t = threadIdx.x;
    if (bid >= 2048) { wprep_block(ts2, SA, SB, bid - 2048, t, swA, swB); return; }
    const int ch = bid & (CH - 1), h = bid >> 9;
    const int d = t, k0 = ch * CHR;
    const float tmax = ts2[h * NND + NND - 1];
    float aA = 0.f, aB = 0.f;
#pragma unroll
    for (int r = 0; r < CHR; r++) {
        float u = ts2[h * NND + k0 + r] - tmax;
        float wa = expf(u), wb = expf(LEAKY * u);
        int j = perm2[h * NND + k0 + r];
        float v = Wx2[(size_t)j * C2 + h * D2 + d];
        aA += wa * v; aB += wb * v;
    }
    cTA[(h * CH + ch) * D2 + d] = aA;
    cTB[(h * CH + ch) * D2 + d] = aB;
}

// ---------------- k10: layer-2 scan p3 ----------------
__global__ __launch_bounds__(256) void k10_scan2_p3(const float* __restrict__ Wx2,
        const float* __restrict__ ts2, const int* __restrict__ perm2,
        const float* __restrict__ cTA, const float* __restrict__ cTB,
        const float* __restrict__ TotA,
        float* __restrict__ A, float* __restrict__ B) {
    const int bid = blockIdx.x, t = threadIdx.x;
    const int ch = bid & (CH - 1), h = bid >> 9;
    const int d = t;
    const float tmax = ts2[h * NND + NND - 1];
    float runA = cTA[(h * CH + ch) * D2 + d];
    float runB = cTB[(h * CH + ch) * D2 + d];
    const float totA = TotA[h * D2 + d];
    const int k0 = ch * CHR;
    float v[CHR], wa[CHR], wb[CHR];
#pragma unroll
    for (int r = 0; r < CHR; r++) {
        float u = ts2[h * NND + k0 + r] - tmax;
        wa[r] = expf(u); wb[r] = expf(LEAKY * u);
        int j = perm2[h * NND + k0 + r];
        v[r] = Wx2[(size_t)j * C2 + h * D2 + d];
    }
#pragma unroll
    for (int r = 0; r < CHR; r++) {
        size_t o = ((size_t)(h * NP1 + k0 + r)) * D2 + d;
        A[o] = totA - runA;
        B[o] = runB;
        runA += wa[r] * v[r];
        runB += wb[r] * v[r];
    }
    if (ch == CH - 1) {
        size_t o = ((size_t)(h * NP1 + NND)) * D2 + d;
        A[o] = totA - runA;
        B[o] = runB;
    }
}

// ---------------- k11: lookup2 (head-mean + ELU + LayerNorm) ----------------
__global__ __launch_bounds__(256) void k11_lookup2(const float* __restrict__ es,
        const float* __restrict__ ts,
        const float* __restrict__ A, const float* __restrict__ B,
        const float* __restrict__ SA, const float* __restrict__ SB,
        const float* __restrict__ gamma, const float* __restrict__ betap,
        float* __restrict__ out) {
    __shared__ float red[4];
    const int i = blockIdx.x;
    const int t = threadIdx.x;
    const int wid = t >> 6, lane = t & 63;
    float acc = 0.f;
#pragma unroll
    for (int h = 0; h < HEADS; h++) {
        float c = es[h * NND + i];
        float tmax = ts[h * NND + NND - 1];
        float s = c + tmax;
        float m = (s >= 0.f) ? s : LEAKY * s;
        float al = expf(s - m);
        float be = expf(LEAKY * s - m);
        int k = lower_bound_f(ts + h * NND, -c);
        size_t o = ((size_t)(h * NP1 + k)) * D2 + t;
        float num = al * A[o] + be * B[o];
        float den = al * SA[h * NP1 + k] + be * SB[h * NP1 + k];
        acc += num / den;
    }
    acc *= 0.25f;
    float xv = (acc > 0.f) ? acc : expm1f(acc);
    float sv = wave_sum(xv);
    if (lane == 0) red[wid] = sv;
    __syncthreads();
    float mu = (red[0] + red[1] + red[2] + red[3]) * (1.f / 256.f);
    __syncthreads();
    float dv = xv - mu;
    float s2 = wave_sum(dv * dv);
    if (lane == 0) red[wid] = s2;
    __syncthreads();
    float var = (red[0] + red[1] + red[2] + red[3]) * (1.f / 256.f);
    out[i * D2 + t] = gamma[t] * dv * rsqrtf(var + LN_EPS) + betap[t];
}

extern "C" void kernel_launch(void* const* d_in, const int* in_sizes, int n_in,
                              void* d_out, int out_size, void* d_ws, size_t ws_size,
                              hipStream_t stream) {
    const float* x     = (const float*)d_in[0];
    const float* W1    = (const float*)d_in[1];
    const float* attn1 = (const float*)d_in[2];
    const float* W2    = (const float*)d_in[3];
    const float* attn2 = (const float*)d_in[4];
    const float* gamma = (const float*)d_in[5];
    const float* betap = (const float*)d_in[6];
    float* out = (float*)d_out;

    char* ws = (char*)d_ws;
    size_t off = 0;
    auto alloc = [&](size_t nbytes) -> void* {
        void* p = (void*)(ws + off);
        off += (nbytes + 255) & ~(size_t)255;
        return p;
    };

    float* Wx1 = (float*)alloc((size_t)NND * HID * 4);
    float* Wx2 = (float*)alloc((size_t)NND * C2 * 4);
    unsigned short* h1h = (unsigned short*)alloc((size_t)NND * HID * 2);
    unsigned short* h1l = (unsigned short*)alloc((size_t)NND * HID * 2);
    float* es1 = (float*)alloc((size_t)HEADS * NND * 4);
    float* et1 = (float*)alloc((size_t)HEADS * NND * 4);
    float* es2 = (float*)alloc((size_t)HEADS * NND * 4);
    float* et2 = (float*)alloc((size_t)HEADS * NND * 4);
    float* ts1 = (float*)alloc((size_t)HEADS * NND * 4);
    float* ts2 = (float*)alloc((size_t)HEADS * NND * 4);
    int* perm1 = (int*)alloc((size_t)HEADS * NND * 4);
    int* perm2 = (int*)alloc((size_t)HEADS * NND * 4);
    float* A   = (float*)alloc((size_t)HEADS * NP1 * D2 * 4);
    float* B   = (float*)alloc((size_t)HEADS * NP1 * D2 * 4);
    float* SA  = (float*)alloc((size_t)HEADS * NP1 * 4);
    float* SB  = (float*)alloc((size_t)HEADS * NP1 * 4);
    float* cTA = (float*)alloc((size_t)HEADS * CH * D2 * 4);
    float* cTB = (float*)alloc((size_t)HEADS * CH * D2 * 4);
    float* TotA = (float*)alloc((size_t)HEADS * D2 * 4);
    float* TotB = (float*)alloc((size_t)HEADS * D2 * 4);
    unsigned short* W2h = (unsigned short*)alloc((size_t)262144 * 2);
    unsigned short* W2l = (unsigned short*)alloc((size_t)262144 * 2);
    float* w_es = (float*)alloc((size_t)HEADS * HID * 4);
    float* w_et = (float*)alloc((size_t)HEADS * HID * 4);
    (void)ws_size; (void)in_sizes; (void)n_in; (void)out_size;

    // ---- layer 1 ----
    k1_gemm1_prep<<<1792, 256, 0, stream>>>(x, W1, attn1, W2, attn2,
                                            Wx1, es1, et1, W2h, W2l, w_es, w_et);
    k2_sort<<<256, 256, 0, stream>>>(et1, ts1, perm1);
    k3_scan1_p1<<<CH + 4, 256, 0, stream>>>(Wx1, ts1, perm1, cTA, cTB, SA, SB);
    k_scan_p2<<<64, 256, 0, stream>>>(cTA, cTB, TotA, TotB, 6);
    k5_scan1_p3<<<CH, 256, 0, stream>>>(Wx1, ts1, perm1, cTA, cTB, TotA, A, B);
    k6_lookup1<<<NND, 256, 0, stream>>>(es1, ts1, A, B, SA, SB, w_es, w_et,
                                        h1h, h1l, es2, et2);

    // ---- layer 2 ----
    k7_gemm2_sort2<<<1280, 256, 0, stream>>>(h1h, h1l, W2h, W2l, Wx2, et2, ts2, perm2);
    k8_scan2_p1<<<2052, 256, 0, stream>>>(Wx2, ts2, perm2, cTA, cTB, SA, SB);
    k_scan_p2<<<256, 256, 0, stream>>>(cTA, cTB, TotA, TotB, 8);
    k10_scan2_p3<<<2048, 256, 0, stream>>>(Wx2, ts2, perm2, cTA, cTB, TotA, A, B);
    k11_lookup2<<<NND, 256, 0, stream>>>(es2, ts2, A, B, SA, SB, gamma, betap, out);
}

// Round 8
// 185.700 us; speedup vs baseline: 5.9799x; 1.0293x over previous
//
#include <hip/hip_runtime.h>
#include <math.h>

#define NND 4096
#define SDIM 128
#define HEADS 4
#define D1 64
#define HID 256
#define D2 256
#define C2 1024
#define NP1 (NND + 1)
#define CH 512
#define CHR 8
#define LEAKY 0.2f
#define LN_EPS 1e-5f

typedef __attribute__((ext_vector_type(8))) short bf16x8;
typedef __attribute__((ext_vector_type(4))) float f32x4;
typedef __attribute__((ext_vector_type(8))) unsigned short u16x8;

__device__ __forceinline__ unsigned short f2bf(float f) {
    union { float f; unsigned u; } v; v.f = f;
    unsigned r = v.u + 0x7FFFu + ((v.u >> 16) & 1u);
    return (unsigned short)(r >> 16);
}
__device__ __forceinline__ float bf2f(unsigned short s) {
    union { unsigned u; float f; } v; v.u = ((unsigned)s) << 16; return v.f;
}
__device__ __forceinline__ float wave_sum(float v) {
#pragma unroll
    for (int o = 32; o > 0; o >>= 1) v += __shfl_xor(v, o, 64);
    return v;
}
__device__ __forceinline__ int lower_bound_f(const float* __restrict__ a, float x) {
    int lo = 0, hi = NND;
    while (lo < hi) {
        int mid = (lo + hi) >> 1;
        if (a[mid] < x) lo = mid + 1; else hi = mid;
    }
    return lo;
}
// fragment-linear chunk index: 16-row group, 8-k group
__device__ __forceinline__ int chunk_of(int row, int kg) {
    return ((row >> 4) << 6) + (kg << 4) + (row & 15);
}

#define MM(a, b, c) c = __builtin_amdgcn_mfma_f32_16x16x32_bf16(a, b, c, 0, 0, 0)

// ---------------- sort: rank of 64 elems/block vs all keys (sortable uint) ----------------
__device__ __forceinline__ void sort_block(unsigned* key, int* pr,
        const float* __restrict__ et,
        float* __restrict__ ts, int* __restrict__ perm, int h, int e0, int t) {
    for (int p = t; p < NND; p += 256) {
        unsigned u = __float_as_uint(et[h * NND + p]);
        key[p] = (u & 0x80000000u) ? ~u : (u | 0x80000000u);
    }
    if (t < 64) pr[t] = 0;
    __syncthreads();
    const int e = t & 63, sg = t >> 6;
    const int myIdx = e0 + e;
    const unsigned myU = key[myIdx];
    int rank = 0;
    const int kbeg = sg * (NND / 4);
#pragma unroll 8
    for (int k = kbeg; k < kbeg + NND / 4; k++) {
        unsigned v = key[k];
        rank += (v < myU || (v == myU && k < myIdx)) ? 1 : 0;
    }
    atomicAdd(&pr[e], rank);
    __syncthreads();
    if (t < 64) {
        int r = pr[t];
        unsigned u = key[e0 + t];
        float f = (u & 0x80000000u) ? __uint_as_float(u ^ 0x80000000u)
                                    : __uint_as_float(~u);
        ts[h * NND + r] = f;
        perm[h * NND + r] = e0 + t;
    }
}

// ---------------- per-head scalar weight scan ----------------
__device__ __forceinline__ void wprep_block(const float* __restrict__ ts,
        float* __restrict__ SA, float* __restrict__ SB, int h, int t,
        float* swA, float* swB) {
    const int lane = t & 63, w = t >> 6;
    const float tmax = ts[h * NND + NND - 1];
    float a[16], b[16];
    float la = 0.f, lb = 0.f;
    const int kb = t * 16;
#pragma unroll
    for (int q = 0; q < 16; q++) {
        float u = ts[h * NND + kb + q] - tmax;
        a[q] = expf(u); b[q] = expf(LEAKY * u);
        la += a[q]; lb += b[q];
    }
    float sa = la, sb = lb;
#pragma unroll
    for (int o = 1; o < 64; o <<= 1) {
        float ua = __shfl_up(sa, o, 64);
        float ub = __shfl_up(sb, o, 64);
        if (lane >= o) { sa += ua; sb += ub; }
    }
    if (lane == 63) { swA[w] = sa; swB[w] = sb; }
    __syncthreads();
    float baseA = 0.f, baseB = 0.f, totA = 0.f, totB = 0.f;
#pragma unroll
    for (int ww = 0; ww < 4; ww++) {
        float va = swA[ww], vb = swB[ww];
        totA += va; totB += vb;
        if (ww < w) { baseA += va; baseB += vb; }
    }
    float preA = baseA + sa - la;
    float preB = baseB + sb - lb;
#pragma unroll
    for (int q = 0; q < 16; q++) {
        SA[h * NP1 + kb + q] = totA - preA;
        SB[h * NP1 + kb + q] = preB;
        preA += a[q]; preB += b[q];
    }
    if (t == 255) { SA[h * NP1 + NND] = 0.f; SB[h * NP1 + NND] = totB; }
}

// ---------------- k1: gemm1 (fragment-linear LDS, fused escore1) | W2 prep | fold --------
__global__ __launch_bounds__(256) void k1_gemm1_prep(
        const float* __restrict__ x, const float* __restrict__ W1,
        const float* __restrict__ attn1,
        const float* __restrict__ W2, const float* __restrict__ attn2,
        float* __restrict__ Wx1, float* __restrict__ es1, float* __restrict__ et1,
        unsigned short* __restrict__ W2h, unsigned short* __restrict__ W2l,
        float* __restrict__ w_es, float* __restrict__ w_et) {
    __shared__ unsigned short Ah[256][8], Al[256][8], Bh[256][8], Bl[256][8];
    __shared__ float esP[2][2][32], etP[2][2][32];
    const int bid = blockIdx.x, t = threadIdx.x;
    if (bid < 256) {
        const int lane = t & 63, w = t >> 6;
        const int wm = w >> 1, wn = w & 1;
        const int h = bid & 3, n0 = h * 64, m0 = (bid >> 2) * 64;
        const int fr = lane & 15, kg = lane >> 4;
        const int srow = t & 63, skg = t >> 6;
        const int sc = chunk_of(srow, skg);
        f32x4 z4 = {0.f, 0.f, 0.f, 0.f};
        f32x4 acc[2][2] = {{z4, z4}, {z4, z4}};
        for (int k0 = 0; k0 < SDIM; k0 += 32) {
            {   // A: 8 floats of row srow
                float fv[8];
                *(float4*)&fv[0] = *(const float4*)&x[(size_t)(m0 + srow) * SDIM + k0 + skg * 8];
                *(float4*)&fv[4] = *(const float4*)&x[(size_t)(m0 + srow) * SDIM + k0 + skg * 8 + 4];
                u16x8 ph, pl;
#pragma unroll
                for (int i = 0; i < 8; i++) {
                    unsigned short hi = f2bf(fv[i]);
                    ph[i] = hi; pl[i] = f2bf(fv[i] - bf2f(hi));
                }
                *(u16x8*)&Ah[sc][0] = ph;
                *(u16x8*)&Al[sc][0] = pl;
            }
            {   // B: 8 k's of column n0+srow (coalesced per k across lanes)
                u16x8 ph, pl;
#pragma unroll
                for (int i = 0; i < 8; i++) {
                    float v = W1[(size_t)(k0 + skg * 8 + i) * HID + n0 + srow];
                    unsigned short hi = f2bf(v);
                    ph[i] = hi; pl[i] = f2bf(v - bf2f(hi));
                }
                *(u16x8*)&Bh[sc][0] = ph;
                *(u16x8*)&Bl[sc][0] = pl;
            }
            __syncthreads();
            bf16x8 ah0 = *(bf16x8*)&Ah[wm * 128 + lane][0];
            bf16x8 ah1 = *(bf16x8*)&Ah[wm * 128 + 64 + lane][0];
            bf16x8 al0 = *(bf16x8*)&Al[wm * 128 + lane][0];
            bf16x8 al1 = *(bf16x8*)&Al[wm * 128 + 64 + lane][0];
            bf16x8 bh0 = *(bf16x8*)&Bh[wn * 128 + lane][0];
            bf16x8 bh1 = *(bf16x8*)&Bh[wn * 128 + 64 + lane][0];
            bf16x8 bl0 = *(bf16x8*)&Bl[wn * 128 + lane][0];
            bf16x8 bl1 = *(bf16x8*)&Bl[wn * 128 + 64 + lane][0];
            MM(ah0, bh0, acc[0][0]); MM(ah0, bl0, acc[0][0]); MM(al0, bh0, acc[0][0]);
            MM(ah0, bh1, acc[0][1]); MM(ah0, bl1, acc[0][1]); MM(al0, bh1, acc[0][1]);
            MM(ah1, bh0, acc[1][0]); MM(ah1, bl0, acc[1][0]); MM(al1, bh0, acc[1][0]);
            MM(ah1, bh1, acc[1][1]); MM(ah1, bl1, acc[1][1]); MM(al1, bh1, acc[1][1]);
            __syncthreads();
        }
        const float as0 = attn1[h * 128 + wn * 32 + fr];
        const float as1 = attn1[h * 128 + wn * 32 + 16 + fr];
        const float at0 = attn1[h * 128 + 64 + wn * 32 + fr];
        const float at1 = attn1[h * 128 + 64 + wn * 32 + 16 + fr];
#pragma unroll
        for (int mb = 0; mb < 2; mb++) {
#pragma unroll
            for (int r = 0; r < 4; r++) {
                int row = m0 + wm * 32 + mb * 16 + kg * 4 + r;
#pragma unroll
                for (int nb = 0; nb < 2; nb++)
                    Wx1[(size_t)row * HID + n0 + wn * 32 + nb * 16 + fr] = acc[mb][nb][r];
                float ve = acc[mb][0][r] * as0 + acc[mb][1][r] * as1;
                float vt = acc[mb][0][r] * at0 + acc[mb][1][r] * at1;
#pragma unroll
                for (int msk = 1; msk < 16; msk <<= 1) {
                    ve += __shfl_xor(ve, msk, 64);
                    vt += __shfl_xor(vt, msk, 64);
                }
                if (fr == 0) {
                    esP[wm][wn][mb * 16 + kg * 4 + r] = ve;
                    etP[wm][wn][mb * 16 + kg * 4 + r] = vt;
                }
            }
        }
        __syncthreads();
        if (t < 64) {
            int wmm = t >> 5, ri = t & 31;
            es1[h * NND + m0 + t] = esP[wmm][0][ri] + esP[wmm][1][ri];
            et1[h * NND + m0 + t] = etP[wmm][0][ri] + etP[wmm][1][ri];
        }
    } else if (bid < 1280) {
        int j = (bid - 256) * 256 + t;
        int n = j >> 8, k = j & 255;
        float v = W2[(size_t)k * C2 + n];
        unsigned short hi = f2bf(v);
        W2h[j] = hi; W2l[j] = f2bf(v - bf2f(hi));
    } else {
        int g = (bid - 1280) * 4 + (t >> 6);
        int lane = t & 63;
        int k = g & 255, hs = g >> 8, h = hs >> 1, sel = hs & 1;
        float acc = 0.f;
#pragma unroll
        for (int qq = 0; qq < 4; qq++)
            acc += W2[(size_t)k * C2 + h * 256 + qq * 64 + lane] *
                   attn2[h * 512 + sel * 256 + qq * 64 + lane];
        acc = wave_sum(acc);
        if (lane == 0) {
            if (sel) w_et[h * 256 + k] = acc;
            else     w_es[h * 256 + k] = acc;
        }
    }
}

// ---------------- k2: sort (layer 1) ----------------
__global__ __launch_bounds__(256) void k2_sort(const float* __restrict__ et,
        float* __restrict__ ts, int* __restrict__ perm) {
    __shared__ unsigned key[NND];
    __shared__ int pr[64];
    const int bid = blockIdx.x, t = threadIdx.x;
    sort_block(key, pr, et, ts, perm, bid >> 6, (bid & 63) * 64, t);
}

// ---------------- k3: layer-1 scan p1 (4h x 64d) + wprep1 ----------------
__global__ __launch_bounds__(256) void k3_scan1_p1(const float* __restrict__ Wx1,
        const float* __restrict__ ts1, const int* __restrict__ perm1,
        float* __restrict__ cTA, float* __restrict__ cTB,
        float* __restrict__ SA, float* __restrict__ SB) {
    __shared__ float swA[4], swB[4];
    const int bid = blockIdx.x, t = threadIdx.x;
    if (bid >= CH) { wprep_block(ts1, SA, SB, bid - CH, t, swA, swB); return; }
    const int h = t >> 6, d = t & 63;
    const int k0 = bid * CHR;
    const float tmax = ts1[h * NND + NND - 1];
    float aA = 0.f, aB = 0.f;
#pragma unroll
    for (int r = 0; r < CHR; r++) {
        float u = ts1[h * NND + k0 + r] - tmax;
        float wa = expf(u), wb = expf(LEAKY * u);
        int j = perm1[h * NND + k0 + r];
        float v = Wx1[(size_t)j * HID + h * D1 + d];
        aA += wa * v; aB += wb * v;
    }
    cTA[(h * CH + bid) * D1 + d] = aA;
    cTB[(h * CH + bid) * D1 + d] = aB;
}

// ---------------- p2: wave-parallel exclusive scan of chunk totals (in place) ------------
__global__ __launch_bounds__(256) void k_scan_p2(float* __restrict__ cTA,
        float* __restrict__ cTB, float* __restrict__ TotA, float* __restrict__ TotB,
        int logD) {
    const int t = threadIdx.x;
    const int lane = t & 63, w = t >> 6;
    const int D = 1 << logD;
    const int col = blockIdx.x * 4 + w;
    const int h = col >> logD, d = col & (D - 1);
    const size_t base = (size_t)h * CH * D + d;
    float vA[8], vB[8];
#pragma unroll
    for (int q = 0; q < 8; q++) {
        size_t o = base + (size_t)(lane * 8 + q) * D;
        vA[q] = cTA[o];
        vB[q] = cTB[o];
    }
    float laA = 0.f, laB = 0.f;
#pragma unroll
    for (int q = 0; q < 8; q++) { laA += vA[q]; laB += vB[q]; }
    float sA = laA, sB = laB;
#pragma unroll
    for (int o = 1; o < 64; o <<= 1) {
        float uA = __shfl_up(sA, o, 64);
        float uB = __shfl_up(sB, o, 64);
        if (lane >= o) { sA += uA; sB += uB; }
    }
    float totA = __shfl(sA, 63, 64);
    float totB = __shfl(sB, 63, 64);
    float runA = sA - laA, runB = sB - laB;
#pragma unroll
    for (int q = 0; q < 8; q++) {
        size_t o = base + (size_t)(lane * 8 + q) * D;
        float tA = vA[q], tB = vB[q];
        cTA[o] = runA;
        cTB[o] = runB;
        runA += tA; runB += tB;
    }
    if (lane == 0) {
        TotA[h * D + d] = totA;
        TotB[h * D + d] = totB;
    }
}

// ---------------- k5: layer-1 scan p3 ----------------
__global__ __launch_bounds__(256) void k5_scan1_p3(const float* __restrict__ Wx1,
        const float* __restrict__ ts1, const int* __restrict__ perm1,
        const float* __restrict__ cTA, const float* __restrict__ cTB,
        const float* __restrict__ TotA,
        float* __restrict__ A, float* __restrict__ B) {
    const int ch = blockIdx.x, t = threadIdx.x;
    const int h = t >> 6, d = t & 63;
    const float tmax = ts1[h * NND + NND - 1];
    float runA = cTA[(h * CH + ch) * D1 + d];
    float runB = cTB[(h * CH + ch) * D1 + d];
    const float totA = TotA[h * D1 + d];
    const int k0 = ch * CHR;
    float v[CHR], wa[CHR], wb[CHR];
#pragma unroll
    for (int r = 0; r < CHR; r++) {
        float u = ts1[h * NND + k0 + r] - tmax;
        wa[r] = expf(u); wb[r] = expf(LEAKY * u);
        int j = perm1[h * NND + k0 + r];
        v[r] = Wx1[(size_t)j * HID + h * D1 + d];
    }
#pragma unroll
    for (int r = 0; r < CHR; r++) {
        size_t o = ((size_t)(h * NP1 + k0 + r)) * D1 + d;
        A[o] = totA - runA;
        B[o] = runB;
        runA += wa[r] * v[r];
        runB += wb[r] * v[r];
    }
    if (ch == CH - 1) {
        size_t o = ((size_t)(h * NP1 + NND)) * D1 + d;
        A[o] = totA - runA;
        B[o] = runB;
    }
}

// ---------------- k6: lookup1 -> h1 (split bf16) + fused escore2 (per-wave head) ---------
__global__ __launch_bounds__(256) void k6_lookup1(const float* __restrict__ es,
        const float* __restrict__ ts,
        const float* __restrict__ A, const float* __restrict__ Bv,
        const float* __restrict__ SA, const float* __restrict__ SB,
        const float* __restrict__ w_es, const float* __restrict__ w_et,
        unsigned short* __restrict__ h1h, unsigned short* __restrict__ h1l,
        float* __restrict__ es2, float* __restrict__ et2) {
    __shared__ float hbuf[256];
    const int i = blockIdx.x, t = threadIdx.x;
    const int h = t >> 6, d = t & 63;
    const int lane = t & 63, wid = t >> 6;
    float c = es[h * NND + i];
    float tmax = ts[h * NND + NND - 1];
    float s = c + tmax;
    float m = (s >= 0.f) ? s : LEAKY * s;
    float al = expf(s - m);
    float be = expf(LEAKY * s - m);
    int k = lower_bound_f(ts + h * NND, -c);
    size_t o = ((size_t)(h * NP1 + k)) * D1 + d;
    float num = al * A[o] + be * Bv[o];
    float den = al * SA[h * NP1 + k] + be * SB[h * NP1 + k];
    float val = num / den;
    float hv = (val > 0.f) ? val : expm1f(val);
    unsigned short hh = f2bf(hv);
    h1h[i * HID + t] = hh;
    h1l[i * HID + t] = f2bf(hv - bf2f(hh));
    hbuf[t] = hv;
    __syncthreads();
    // wave `wid` computes es2/et2 for head `wid`
    float4 hv4 = *(const float4*)&hbuf[lane * 4];
    float4 we4 = *(const float4*)&w_es[wid * HID + lane * 4];
    float4 wt4 = *(const float4*)&w_et[wid * HID + lane * 4];
    float pes = hv4.x * we4.x + hv4.y * we4.y + hv4.z * we4.z + hv4.w * we4.w;
    float pet = hv4.x * wt4.x + hv4.y * wt4.y + hv4.z * wt4.z + hv4.w * wt4.w;
    pes = wave_sum(pes);
    pet = wave_sum(pet);
    if (lane == 0) {
        es2[wid * NND + i] = pes;
        et2[wid * NND + i] = pet;
    }
}

// ---------------- k7: gemm2 128x64 tile (fragment-linear LDS) | sort2 ----------------
__global__ __launch_bounds__(256) void k7_gemm2_sort2(
        const unsigned short* __restrict__ h1h, const unsigned short* __restrict__ h1l,
        const unsigned short* __restrict__ W2h, const unsigned short* __restrict__ W2l,
        float* __restrict__ Wx2,
        const float* __restrict__ et2, float* __restrict__ ts2, int* __restrict__ perm2) {
    union SM7 {
        struct { unsigned short Ah[512][8], Al[512][8], Bh[256][8], Bl[256][8]; } g;
        struct { unsigned key[NND]; int pr[64]; } s;
    };
    __shared__ SM7 sm;
    const int bid = blockIdx.x, t = threadIdx.x;
    if (bid >= 512) {
        sort_block(sm.s.key, sm.s.pr, et2, ts2, perm2,
                   (bid - 512) >> 6, ((bid - 512) & 63) * 64, t);
        return;
    }
    const int lane = t & 63, w = t >> 6;
    const int n0 = (bid & 15) * 64, m0 = (bid >> 4) * 128;
    const int fr = lane & 15, kg = lane >> 4;
    const int srow = t & 63, skg = t >> 6;
    f32x4 z4 = {0.f, 0.f, 0.f, 0.f};
    f32x4 acc[2][4] = {{z4, z4, z4, z4}, {z4, z4, z4, z4}};
    for (int k0 = 0; k0 < HID; k0 += 32) {
        {
#pragma unroll
            for (int rr = 0; rr < 2; rr++) {
                int rowa = rr * 64 + srow;
                int c = chunk_of(rowa, skg);
                *(u16x8*)&sm.g.Ah[c][0] =
                    *(const u16x8*)&h1h[(size_t)(m0 + rowa) * HID + k0 + skg * 8];
                *(u16x8*)&sm.g.Al[c][0] =
                    *(const u16x8*)&h1l[(size_t)(m0 + rowa) * HID + k0 + skg * 8];
            }
            int cb = chunk_of(srow, skg);
            *(u16x8*)&sm.g.Bh[cb][0] =
                *(const u16x8*)&W2h[(size_t)(n0 + srow) * HID + k0 + skg * 8];
            *(u16x8*)&sm.g.Bl[cb][0] =
                *(const u16x8*)&W2l[(size_t)(n0 + srow) * HID + k0 + skg * 8];
        }
        __syncthreads();
        bf16x8 ah[2], al[2], bh[4], bl[4];
#pragma unroll
        for (int mb = 0; mb < 2; mb++) {
            ah[mb] = *(bf16x8*)&sm.g.Ah[w * 128 + mb * 64 + lane][0];
            al[mb] = *(bf16x8*)&sm.g.Al[w * 128 + mb * 64 + lane][0];
        }
#pragma unroll
        for (int nb = 0; nb < 4; nb++) {
            bh[nb] = *(bf16x8*)&sm.g.Bh[nb * 64 + lane][0];
            bl[nb] = *(bf16x8*)&sm.g.Bl[nb * 64 + lane][0];
        }
#pragma unroll
        for (int mb = 0; mb < 2; mb++)
#pragma unroll
            for (int nb = 0; nb < 4; nb++) {
                MM(ah[mb], bh[nb], acc[mb][nb]);
                MM(ah[mb], bl[nb], acc[mb][nb]);
                MM(al[mb], bh[nb], acc[mb][nb]);
            }
        __syncthreads();
    }
#pragma unroll
    for (int mb = 0; mb < 2; mb++)
#pragma unroll
        for (int r = 0; r < 4; r++) {
            int row = m0 + w * 32 + mb * 16 + kg * 4 + r;
#pragma unroll
            for (int nb = 0; nb < 4; nb++)
                Wx2[(size_t)row * C2 + n0 + nb * 16 + fr] = acc[mb][nb][r];
        }
}

// ---------------- k8: layer-2 scan p1 + wprep2 ----------------
__global__ __launch_bounds__(256) void k8_scan2_p1(const float* __restrict__ Wx2,
        const float* __restrict__ ts2, const int* __restrict__ perm2,
        float* __restrict__ cTA, float* __restrict__ cTB,
        float* __restrict__ SA, float* __restrict__ SB) {
    __shared__ float swA[4], swB[4];
    const int bid = blockIdx.x, t = threadIdx.x;
    if (bid >= 2048) { wprep_block(ts2, SA, SB, bid - 2048, t, swA, swB); return; }
    const int ch = bid & (CH - 1), h = bid >> 9;
    const int d = t, k0 = ch * CHR;
    const float tmax = ts2[h * NND + NND - 1];
    float aA = 0.f, aB = 0.f;
#pragma unroll
    for (int r = 0; r < CHR; r++) {
        float u = ts2[h * NND + k0 + r] - tmax;
        float wa = expf(u), wb = expf(LEAKY * u);
        int j = perm2[h * NND + k0 + r];
        float v = Wx2[(size_t)j * C2 + h * D2 + d];
        aA += wa * v; aB += wb * v;
    }
    cTA[(h * CH + ch) * D2 + d] = aA;
    cTB[(h * CH + ch) * D2 + d] = aB;
}

// ---------------- k10: layer-2 scan p3 ----------------
__global__ __launch_bounds__(256) void k10_scan2_p3(const float* __restrict__ Wx2,
        const float* __restrict__ ts2, const int* __restrict__ perm2,
        const float* __restrict__ cTA, const float* __restrict__ cTB,
        const float* __restrict__ TotA,
        float* __restrict__ A, float* __restrict__ B) {
    const int bid = blockIdx.x, t = threadIdx.x;
    const int ch = bid & (CH - 1), h = bid >> 9;
    const int d = t;
    const float tmax = ts2[h * NND + NND - 1];
    float runA = cTA[(h * CH + ch) * D2 + d];
    float runB = cTB[(h * CH + ch) * D2 + d];
    const float totA = TotA[h * D2 + d];
    const int k0 = ch * CHR;
    float v[CHR], wa[CHR], wb[CHR];
#pragma unroll
    for (int r = 0; r < CHR; r++) {
        float u = ts2[h * NND + k0 + r] - tmax;
        wa[r] = expf(u); wb[r] = expf(LEAKY * u);
        int j = perm2[h * NND + k0 + r];
        v[r] = Wx2[(size_t)j * C2 + h * D2 + d];
    }
#pragma unroll
    for (int r = 0; r < CHR; r++) {
        size_t o = ((size_t)(h * NP1 + k0 + r)) * D2 + d;
        A[o] = totA - runA;
        B[o] = runB;
        runA += wa[r] * v[r];
        runB += wb[r] * v[r];
    }
    if (ch == CH - 1) {
        size_t o = ((size_t)(h * NP1 + NND)) * D2 + d;
        A[o] = totA - runA;
        B[o] = runB;
    }
}

// ---------------- k11: lookup2 (head-mean + ELU + LayerNorm) ----------------
__global__ __launch_bounds__(256) void k11_lookup2(const float* __restrict__ es,
        const float* __restrict__ ts,
        const float* __restrict__ A, const float* __restrict__ B,
        const float* __restrict__ SA, const float* __restrict__ SB,
        const float* __restrict__ gamma, const float* __restrict__ betap,
        float* __restrict__ out) {
    __shared__ float red[4];
    const int i = blockIdx.x;
    const int t = threadIdx.x;
    const int wid = t >> 6, lane = t & 63;
    float acc = 0.f;
#pragma unroll
    for (int h = 0; h < HEADS; h++) {
        float c = es[h * NND + i];
        float tmax = ts[h * NND + NND - 1];
        float s = c + tmax;
        float m = (s >= 0.f) ? s : LEAKY * s;
        float al = expf(s - m);
        float be = expf(LEAKY * s - m);
        int k = lower_bound_f(ts + h * NND, -c);
        size_t o = ((size_t)(h * NP1 + k)) * D2 + t;
        float num = al * A[o] + be * B[o];
        float den = al * SA[h * NP1 + k] + be * SB[h * NP1 + k];
        acc += num / den;
    }
    acc *= 0.25f;
    float xv = (acc > 0.f) ? acc : expm1f(acc);
    float sv = wave_sum(xv);
    if (lane == 0) red[wid] = sv;
    __syncthreads();
    float mu = (red[0] + red[1] + red[2] + red[3]) * (1.f / 256.f);
    __syncthreads();
    float dv = xv - mu;
    float s2 = wave_sum(dv * dv);
    if (lane == 0) red[wid] = s2;
    __syncthreads();
    float var = (red[0] + red[1] + red[2] + red[3]) * (1.f / 256.f);
    out[i * D2 + t] = gamma[t] * dv * rsqrtf(var + LN_EPS) + betap[t];
}

extern "C" void kernel_launch(void* const* d_in, const int* in_sizes, int n_in,
                              void* d_out, int out_size, void* d_ws, size_t ws_size,
                              hipStream_t stream) {
    const float* x     = (const float*)d_in[0];
    const float* W1    = (const float*)d_in[1];
    const float* attn1 = (const float*)d_in[2];
    const float* W2    = (const float*)d_in[3];
    const float* attn2 = (const float*)d_in[4];
    const float* gamma = (const float*)d_in[5];
    const float* betap = (const float*)d_in[6];
    float* out = (float*)d_out;

    char* ws = (char*)d_ws;
    size_t off = 0;
    auto alloc = [&](size_t nbytes) -> void* {
        void* p = (void*)(ws + off);
        off += (nbytes + 255) & ~(size_t)255;
        return p;
    };

    float* Wx1 = (float*)alloc((size_t)NND * HID * 4);
    float* Wx2 = (float*)alloc((size_t)NND * C2 * 4);
    unsigned short* h1h = (unsigned short*)alloc((size_t)NND * HID * 2);
    unsigned short* h1l = (unsigned short*)alloc((size_t)NND * HID * 2);
    float* es1 = (float*)alloc((size_t)HEADS * NND * 4);
    float* et1 = (float*)alloc((size_t)HEADS * NND * 4);
    float* es2 = (float*)alloc((size_t)HEADS * NND * 4);
    float* et2 = (float*)alloc((size_t)HEADS * NND * 4);
    float* ts1 = (float*)alloc((size_t)HEADS * NND * 4);
    float* ts2 = (float*)alloc((size_t)HEADS * NND * 4);
    int* perm1 = (int*)alloc((size_t)HEADS * NND * 4);
    int* perm2 = (int*)alloc((size_t)HEADS * NND * 4);
    float* A   = (float*)alloc((size_t)HEADS * NP1 * D2 * 4);
    float* B   = (float*)alloc((size_t)HEADS * NP1 * D2 * 4);
    float* SA  = (float*)alloc((size_t)HEADS * NP1 * 4);
    float* SB  = (float*)alloc((size_t)HEADS * NP1 * 4);
    float* cTA = (float*)alloc((size_t)HEADS * CH * D2 * 4);
    float* cTB = (float*)alloc((size_t)HEADS * CH * D2 * 4);
    float* TotA = (float*)alloc((size_t)HEADS * D2 * 4);
    float* TotB = (float*)alloc((size_t)HEADS * D2 * 4);
    unsigned short* W2h = (unsigned short*)alloc((size_t)262144 * 2);
    unsigned short* W2l = (unsigned short*)alloc((size_t)262144 * 2);
    float* w_es = (float*)alloc((size_t)HEADS * HID * 4);
    float* w_et = (float*)alloc((size_t)HEADS * HID * 4);
    (void)ws_size; (void)in_sizes; (void)n_in; (void)out_size;

    // ---- layer 1 ----
    k1_gemm1_prep<<<1792, 256, 0, stream>>>(x, W1, attn1, W2, attn2,
                                            Wx1, es1, et1, W2h, W2l, w_es, w_et);
    k2_sort<<<256, 256, 0, stream>>>(et1, ts1, perm1);
    k3_scan1_p1<<<CH + 4, 256, 0, stream>>>(Wx1, ts1, perm1, cTA, cTB, SA, SB);
    k_scan_p2<<<64, 256, 0, stream>>>(cTA, cTB, TotA, TotB, 6);
    k5_scan1_p3<<<CH, 256, 0, stream>>>(Wx1, ts1, perm1, cTA, cTB, TotA, A, B);
    k6_lookup1<<<NND, 256, 0, stream>>>(es1, ts1, A, B, SA, SB, w_es, w_et,
                                        h1h, h1l, es2, et2);

    // ---- layer 2 ----
    k7_gemm2_sort2<<<768, 256, 0, stream>>>(h1h, h1l, W2h, W2l, Wx2, et2, ts2, perm2);
    k8_scan2_p1<<<2052, 256, 0, stream>>>(Wx2, ts2, perm2, cTA, cTB, SA, SB);
    k_scan_p2<<<256, 256, 0, stream>>>(cTA, cTB, TotA, TotB, 8);
    k10_scan2_p3<<<2048, 256, 0, stream>>>(Wx2, ts2, perm2, cTA, cTB, TotA, A, B);
    k11_lookup2<<<NND, 256, 0, stream>>>(es2, ts2, A, B, SA, SB, gamma, betap, out);
}

// Round 9
// 165.133 us; speedup vs baseline: 6.7247x; 1.1246x over previous
//
#include <hip/hip_runtime.h>
#include <math.h>

#define NND 4096
#define SDIM 128
#define HEADS 4
#define D1 64
#define HID 256
#define D2 256
#define C2 1024
#define NP1 (NND + 1)
#define CH 512
#define CHR 8
#define LEAKY 0.2f
#define LN_EPS 1e-5f

typedef __attribute__((ext_vector_type(8))) short bf16x8;
typedef __attribute__((ext_vector_type(4))) float f32x4;
typedef __attribute__((ext_vector_type(8))) unsigned short u16x8;

__device__ __forceinline__ unsigned short f2bf(float f) {
    union { float f; unsigned u; } v; v.f = f;
    unsigned r = v.u + 0x7FFFu + ((v.u >> 16) & 1u);
    return (unsigned short)(r >> 16);
}
__device__ __forceinline__ float bf2f(unsigned short s) {
    union { unsigned u; float f; } v; v.u = ((unsigned)s) << 16; return v.f;
}
__device__ __forceinline__ float wave_sum(float v) {
#pragma unroll
    for (int o = 32; o > 0; o >>= 1) v += __shfl_xor(v, o, 64);
    return v;
}
__device__ __forceinline__ int lower_bound_f(const float* __restrict__ a, float x) {
    int lo = 0, hi = NND;
    while (lo < hi) {
        int mid = (lo + hi) >> 1;
        if (a[mid] < x) lo = mid + 1; else hi = mid;
    }
    return lo;
}
// fragment-linear chunk index: 16-row group, 8-k group
__device__ __forceinline__ int chunk_of(int row, int kg) {
    return ((row >> 4) << 6) + (kg << 4) + (row & 15);
}

#define MM(a, b, c) c = __builtin_amdgcn_mfma_f32_16x16x32_bf16(a, b, c, 0, 0, 0)

// ---------------- sort: rank of 64 elems/block vs all keys (vectorized b128 reads) -------
__device__ __forceinline__ void sort_block(unsigned* key, int* pr,
        const float* __restrict__ et,
        float* __restrict__ ts, int* __restrict__ perm, int h, int e0, int t) {
    for (int p = t; p < NND; p += 256) {
        unsigned u = __float_as_uint(et[h * NND + p]);
        key[p] = (u & 0x80000000u) ? ~u : (u | 0x80000000u);
    }
    if (t < 64) pr[t] = 0;
    __syncthreads();
    const int e = t & 63, sg = t >> 6;
    const int myIdx = e0 + e;
    const unsigned myU = key[myIdx];
    int rank = 0;
    const int kbeg = sg * (NND / 4);
    for (int kb = kbeg; kb < kbeg + NND / 4; kb += 16) {
        uint4 v0 = *(const uint4*)&key[kb];
        uint4 v1 = *(const uint4*)&key[kb + 4];
        uint4 v2 = *(const uint4*)&key[kb + 8];
        uint4 v3 = *(const uint4*)&key[kb + 12];
        unsigned vv[16] = {v0.x, v0.y, v0.z, v0.w, v1.x, v1.y, v1.z, v1.w,
                           v2.x, v2.y, v2.z, v2.w, v3.x, v3.y, v3.z, v3.w};
#pragma unroll
        for (int q = 0; q < 16; q++) {
            unsigned v = vv[q];
            rank += (int)(v < myU) + (int)((v == myU) & ((kb + q) < myIdx));
        }
    }
    atomicAdd(&pr[e], rank);
    __syncthreads();
    if (t < 64) {
        int r = pr[t];
        unsigned u = key[e0 + t];
        float f = (u & 0x80000000u) ? __uint_as_float(u ^ 0x80000000u)
                                    : __uint_as_float(~u);
        ts[h * NND + r] = f;
        perm[h * NND + r] = e0 + t;
    }
}

// ---------------- per-head scalar weight scan ----------------
__device__ __forceinline__ void wprep_block(const float* __restrict__ ts,
        float* __restrict__ SA, float* __restrict__ SB, int h, int t,
        float* swA, float* swB) {
    const int lane = t & 63, w = t >> 6;
    const float tmax = ts[h * NND + NND - 1];
    float a[16], b[16];
    float la = 0.f, lb = 0.f;
    const int kb = t * 16;
#pragma unroll
    for (int q = 0; q < 16; q++) {
        float u = ts[h * NND + kb + q] - tmax;
        a[q] = expf(u); b[q] = expf(LEAKY * u);
        la += a[q]; lb += b[q];
    }
    float sa = la, sb = lb;
#pragma unroll
    for (int o = 1; o < 64; o <<= 1) {
        float ua = __shfl_up(sa, o, 64);
        float ub = __shfl_up(sb, o, 64);
        if (lane >= o) { sa += ua; sb += ub; }
    }
    if (lane == 63) { swA[w] = sa; swB[w] = sb; }
    __syncthreads();
    float baseA = 0.f, baseB = 0.f, totA = 0.f, totB = 0.f;
#pragma unroll
    for (int ww = 0; ww < 4; ww++) {
        float va = swA[ww], vb = swB[ww];
        totA += va; totB += vb;
        if (ww < w) { baseA += va; baseB += vb; }
    }
    float preA = baseA + sa - la;
    float preB = baseB + sb - lb;
#pragma unroll
    for (int q = 0; q < 16; q++) {
        SA[h * NP1 + kb + q] = totA - preA;
        SB[h * NP1 + kb + q] = preB;
        preA += a[q]; preB += b[q];
    }
    if (t == 255) { SA[h * NP1 + NND] = 0.f; SB[h * NP1 + NND] = totB; }
}

// ---------------- k1: gemm1 (fragment-linear LDS, fused escore1) | W2 prep | fold --------
__global__ __launch_bounds__(256) void k1_gemm1_prep(
        const float* __restrict__ x, const float* __restrict__ W1,
        const float* __restrict__ attn1,
        const float* __restrict__ W2, const float* __restrict__ attn2,
        float* __restrict__ Wx1, float* __restrict__ es1, float* __restrict__ et1,
        unsigned short* __restrict__ W2h, unsigned short* __restrict__ W2l,
        float* __restrict__ w_es, float* __restrict__ w_et) {
    __shared__ unsigned short Ah[256][8], Al[256][8], Bh[256][8], Bl[256][8];
    __shared__ float esP[2][2][32], etP[2][2][32];
    const int bid = blockIdx.x, t = threadIdx.x;
    if (bid < 256) {
        const int lane = t & 63, w = t >> 6;
        const int wm = w >> 1, wn = w & 1;
        const int h = bid & 3, n0 = h * 64, m0 = (bid >> 2) * 64;
        const int fr = lane & 15, kg = lane >> 4;
        const int srow = t & 63, skg = t >> 6;
        const int sc = chunk_of(srow, skg);
        f32x4 z4 = {0.f, 0.f, 0.f, 0.f};
        f32x4 acc[2][2] = {{z4, z4}, {z4, z4}};
        for (int k0 = 0; k0 < SDIM; k0 += 32) {
            {   // A: 8 floats of row srow
                float fv[8];
                *(float4*)&fv[0] = *(const float4*)&x[(size_t)(m0 + srow) * SDIM + k0 + skg * 8];
                *(float4*)&fv[4] = *(const float4*)&x[(size_t)(m0 + srow) * SDIM + k0 + skg * 8 + 4];
                u16x8 ph, pl;
#pragma unroll
                for (int i = 0; i < 8; i++) {
                    unsigned short hi = f2bf(fv[i]);
                    ph[i] = hi; pl[i] = f2bf(fv[i] - bf2f(hi));
                }
                *(u16x8*)&Ah[sc][0] = ph;
                *(u16x8*)&Al[sc][0] = pl;
            }
            {   // B: 8 k's of column n0+srow
                u16x8 ph, pl;
#pragma unroll
                for (int i = 0; i < 8; i++) {
                    float v = W1[(size_t)(k0 + skg * 8 + i) * HID + n0 + srow];
                    unsigned short hi = f2bf(v);
                    ph[i] = hi; pl[i] = f2bf(v - bf2f(hi));
                }
                *(u16x8*)&Bh[sc][0] = ph;
                *(u16x8*)&Bl[sc][0] = pl;
            }
            __syncthreads();
            bf16x8 ah0 = *(bf16x8*)&Ah[wm * 128 + lane][0];
            bf16x8 ah1 = *(bf16x8*)&Ah[wm * 128 + 64 + lane][0];
            bf16x8 al0 = *(bf16x8*)&Al[wm * 128 + lane][0];
            bf16x8 al1 = *(bf16x8*)&Al[wm * 128 + 64 + lane][0];
            bf16x8 bh0 = *(bf16x8*)&Bh[wn * 128 + lane][0];
            bf16x8 bh1 = *(bf16x8*)&Bh[wn * 128 + 64 + lane][0];
            bf16x8 bl0 = *(bf16x8*)&Bl[wn * 128 + lane][0];
            bf16x8 bl1 = *(bf16x8*)&Bl[wn * 128 + 64 + lane][0];
            MM(ah0, bh0, acc[0][0]); MM(ah0, bl0, acc[0][0]); MM(al0, bh0, acc[0][0]);
            MM(ah0, bh1, acc[0][1]); MM(ah0, bl1, acc[0][1]); MM(al0, bh1, acc[0][1]);
            MM(ah1, bh0, acc[1][0]); MM(ah1, bl0, acc[1][0]); MM(al1, bh0, acc[1][0]);
            MM(ah1, bh1, acc[1][1]); MM(ah1, bl1, acc[1][1]); MM(al1, bh1, acc[1][1]);
            __syncthreads();
        }
        const float as0 = attn1[h * 128 + wn * 32 + fr];
        const float as1 = attn1[h * 128 + wn * 32 + 16 + fr];
        const float at0 = attn1[h * 128 + 64 + wn * 32 + fr];
        const float at1 = attn1[h * 128 + 64 + wn * 32 + 16 + fr];
#pragma unroll
        for (int mb = 0; mb < 2; mb++) {
#pragma unroll
            for (int r = 0; r < 4; r++) {
                int row = m0 + wm * 32 + mb * 16 + kg * 4 + r;
#pragma unroll
                for (int nb = 0; nb < 2; nb++)
                    Wx1[(size_t)row * HID + n0 + wn * 32 + nb * 16 + fr] = acc[mb][nb][r];
                float ve = acc[mb][0][r] * as0 + acc[mb][1][r] * as1;
                float vt = acc[mb][0][r] * at0 + acc[mb][1][r] * at1;
#pragma unroll
                for (int msk = 1; msk < 16; msk <<= 1) {
                    ve += __shfl_xor(ve, msk, 64);
                    vt += __shfl_xor(vt, msk, 64);
                }
                if (fr == 0) {
                    esP[wm][wn][mb * 16 + kg * 4 + r] = ve;
                    etP[wm][wn][mb * 16 + kg * 4 + r] = vt;
                }
            }
        }
        __syncthreads();
        if (t < 64) {
            int wmm = t >> 5, ri = t & 31;
            es1[h * NND + m0 + t] = esP[wmm][0][ri] + esP[wmm][1][ri];
            et1[h * NND + m0 + t] = etP[wmm][0][ri] + etP[wmm][1][ri];
        }
    } else if (bid < 1280) {
        int j = (bid - 256) * 256 + t;
        int n = j >> 8, k = j & 255;
        float v = W2[(size_t)k * C2 + n];
        unsigned short hi = f2bf(v);
        W2h[j] = hi; W2l[j] = f2bf(v - bf2f(hi));
    } else {
        int g = (bid - 1280) * 4 + (t >> 6);
        int lane = t & 63;
        int k = g & 255, hs = g >> 8, h = hs >> 1, sel = hs & 1;
        float acc = 0.f;
#pragma unroll
        for (int qq = 0; qq < 4; qq++)
            acc += W2[(size_t)k * C2 + h * 256 + qq * 64 + lane] *
                   attn2[h * 512 + sel * 256 + qq * 64 + lane];
        acc = wave_sum(acc);
        if (lane == 0) {
            if (sel) w_et[h * 256 + k] = acc;
            else     w_es[h * 256 + k] = acc;
        }
    }
}

// ---------------- k2: sort (generic, 256 blocks) ----------------
__global__ __launch_bounds__(256) void k2_sort(const float* __restrict__ et,
        float* __restrict__ ts, int* __restrict__ perm) {
    __shared__ unsigned key[NND];
    __shared__ int pr[64];
    const int bid = blockIdx.x, t = threadIdx.x;
    sort_block(key, pr, et, ts, perm, bid >> 6, (bid & 63) * 64, t);
}

// ---------------- k3: layer-1 scan p1 (4h x 64d) + wprep1 ----------------
__global__ __launch_bounds__(256) void k3_scan1_p1(const float* __restrict__ Wx1,
        const float* __restrict__ ts1, const int* __restrict__ perm1,
        float* __restrict__ cTA, float* __restrict__ cTB,
        float* __restrict__ SA, float* __restrict__ SB) {
    __shared__ float swA[4], swB[4];
    const int bid = blockIdx.x, t = threadIdx.x;
    if (bid >= CH) { wprep_block(ts1, SA, SB, bid - CH, t, swA, swB); return; }
    const int h = t >> 6, d = t & 63;
    const int k0 = bid * CHR;
    const float tmax = ts1[h * NND + NND - 1];
    float aA = 0.f, aB = 0.f;
#pragma unroll
    for (int r = 0; r < CHR; r++) {
        float u = ts1[h * NND + k0 + r] - tmax;
        float wa = expf(u), wb = expf(LEAKY * u);
        int j = perm1[h * NND + k0 + r];
        float v = Wx1[(size_t)j * HID + h * D1 + d];
        aA += wa * v; aB += wb * v;
    }
    cTA[(h * CH + bid) * D1 + d] = aA;
    cTB[(h * CH + bid) * D1 + d] = aB;
}

// ---------------- p2: wave-parallel exclusive scan of chunk totals (in place) ------------
__global__ __launch_bounds__(256) void k_scan_p2(float* __restrict__ cTA,
        float* __restrict__ cTB, float* __restrict__ TotA, float* __restrict__ TotB,
        int logD) {
    const int t = threadIdx.x;
    const int lane = t & 63, w = t >> 6;
    const int D = 1 << logD;
    const int col = blockIdx.x * 4 + w;
    const int h = col >> logD, d = col & (D - 1);
    const size_t base = (size_t)h * CH * D + d;
    float vA[8], vB[8];
#pragma unroll
    for (int q = 0; q < 8; q++) {
        size_t o = base + (size_t)(lane * 8 + q) * D;
        vA[q] = cTA[o];
        vB[q] = cTB[o];
    }
    float laA = 0.f, laB = 0.f;
#pragma unroll
    for (int q = 0; q < 8; q++) { laA += vA[q]; laB += vB[q]; }
    float sA = laA, sB = laB;
#pragma unroll
    for (int o = 1; o < 64; o <<= 1) {
        float uA = __shfl_up(sA, o, 64);
        float uB = __shfl_up(sB, o, 64);
        if (lane >= o) { sA += uA; sB += uB; }
    }
    float totA = __shfl(sA, 63, 64);
    float totB = __shfl(sB, 63, 64);
    float runA = sA - laA, runB = sB - laB;
#pragma unroll
    for (int q = 0; q < 8; q++) {
        size_t o = base + (size_t)(lane * 8 + q) * D;
        float tA = vA[q], tB = vB[q];
        cTA[o] = runA;
        cTB[o] = runB;
        runA += tA; runB += tB;
    }
    if (lane == 0) {
        TotA[h * D + d] = totA;
        TotB[h * D + d] = totB;
    }
}

// ---------------- k5: layer-1 scan p3 ----------------
__global__ __launch_bounds__(256) void k5_scan1_p3(const float* __restrict__ Wx1,
        const float* __restrict__ ts1, const int* __restrict__ perm1,
        const float* __restrict__ cTA, const float* __restrict__ cTB,
        const float* __restrict__ TotA,
        float* __restrict__ A, float* __restrict__ B) {
    const int ch = blockIdx.x, t = threadIdx.x;
    const int h = t >> 6, d = t & 63;
    const float tmax = ts1[h * NND + NND - 1];
    float runA = cTA[(h * CH + ch) * D1 + d];
    float runB = cTB[(h * CH + ch) * D1 + d];
    const float totA = TotA[h * D1 + d];
    const int k0 = ch * CHR;
    float v[CHR], wa[CHR], wb[CHR];
#pragma unroll
    for (int r = 0; r < CHR; r++) {
        float u = ts1[h * NND + k0 + r] - tmax;
        wa[r] = expf(u); wb[r] = expf(LEAKY * u);
        int j = perm1[h * NND + k0 + r];
        v[r] = Wx1[(size_t)j * HID + h * D1 + d];
    }
#pragma unroll
    for (int r = 0; r < CHR; r++) {
        size_t o = ((size_t)(h * NP1 + k0 + r)) * D1 + d;
        A[o] = totA - runA;
        B[o] = runB;
        runA += wa[r] * v[r];
        runB += wb[r] * v[r];
    }
    if (ch == CH - 1) {
        size_t o = ((size_t)(h * NP1 + NND)) * D1 + d;
        A[o] = totA - runA;
        B[o] = runB;
    }
}

// ---------------- k6: lookup1 -> h1 (split bf16) + fused escore2 (per-wave head) ---------
__global__ __launch_bounds__(256) void k6_lookup1(const float* __restrict__ es,
        const float* __restrict__ ts,
        const float* __restrict__ A, const float* __restrict__ Bv,
        const float* __restrict__ SA, const float* __restrict__ SB,
        const float* __restrict__ w_es, const float* __restrict__ w_et,
        unsigned short* __restrict__ h1h, unsigned short* __restrict__ h1l,
        float* __restrict__ es2, float* __restrict__ et2) {
    __shared__ float hbuf[256];
    const int i = blockIdx.x, t = threadIdx.x;
    const int h = t >> 6, d = t & 63;
    const int lane = t & 63, wid = t >> 6;
    float c = es[h * NND + i];
    float tmax = ts[h * NND + NND - 1];
    float s = c + tmax;
    float m = (s >= 0.f) ? s : LEAKY * s;
    float al = expf(s - m);
    float be = expf(LEAKY * s - m);
    int k = lower_bound_f(ts + h * NND, -c);
    size_t o = ((size_t)(h * NP1 + k)) * D1 + d;
    float num = al * A[o] + be * Bv[o];
    float den = al * SA[h * NP1 + k] + be * SB[h * NP1 + k];
    float val = num / den;
    float hv = (val > 0.f) ? val : expm1f(val);
    unsigned short hh = f2bf(hv);
    h1h[i * HID + t] = hh;
    h1l[i * HID + t] = f2bf(hv - bf2f(hh));
    hbuf[t] = hv;
    __syncthreads();
    float4 hv4 = *(const float4*)&hbuf[lane * 4];
    float4 we4 = *(const float4*)&w_es[wid * HID + lane * 4];
    float4 wt4 = *(const float4*)&w_et[wid * HID + lane * 4];
    float pes = hv4.x * we4.x + hv4.y * we4.y + hv4.z * we4.z + hv4.w * we4.w;
    float pet = hv4.x * wt4.x + hv4.y * wt4.y + hv4.z * wt4.z + hv4.w * wt4.w;
    pes = wave_sum(pes);
    pet = wave_sum(pet);
    if (lane == 0) {
        es2[wid * NND + i] = pes;
        et2[wid * NND + i] = pet;
    }
}

// ---------------- k7: gemm2 128x64 tile, register-prefetch double-buffer ----------------
__global__ __launch_bounds__(256) void k7_gemm2(
        const unsigned short* __restrict__ h1h, const unsigned short* __restrict__ h1l,
        const unsigned short* __restrict__ W2h, const unsigned short* __restrict__ W2l,
        float* __restrict__ Wx2) {
    __shared__ unsigned short Ah[512][8], Al[512][8], Bh[256][8], Bl[256][8];
    const int bid = blockIdx.x, t = threadIdx.x;
    const int lane = t & 63, w = t >> 6;
    const int n0 = (bid & 15) * 64, m0 = (bid >> 4) * 128;
    const int fr = lane & 15, kg = lane >> 4;
    const int srow = t & 63, skg = t >> 6;
    f32x4 z4 = {0.f, 0.f, 0.f, 0.f};
    f32x4 acc[2][4] = {{z4, z4, z4, z4}, {z4, z4, z4, z4}};
    u16x8 rAh[2], rAl[2], rBh, rBl;
    auto load_step = [&](int k0) {
#pragma unroll
        for (int rr = 0; rr < 2; rr++) {
            rAh[rr] = *(const u16x8*)&h1h[(size_t)(m0 + rr * 64 + srow) * HID + k0 + skg * 8];
            rAl[rr] = *(const u16x8*)&h1l[(size_t)(m0 + rr * 64 + srow) * HID + k0 + skg * 8];
        }
        rBh = *(const u16x8*)&W2h[(size_t)(n0 + srow) * HID + k0 + skg * 8];
        rBl = *(const u16x8*)&W2l[(size_t)(n0 + srow) * HID + k0 + skg * 8];
    };
    load_step(0);
    for (int k0 = 0; k0 < HID; k0 += 32) {
#pragma unroll
        for (int rr = 0; rr < 2; rr++) {
            int c = chunk_of(rr * 64 + srow, skg);
            *(u16x8*)&Ah[c][0] = rAh[rr];
            *(u16x8*)&Al[c][0] = rAl[rr];
        }
        int cb = chunk_of(srow, skg);
        *(u16x8*)&Bh[cb][0] = rBh;
        *(u16x8*)&Bl[cb][0] = rBl;
        __syncthreads();
        if (k0 + 32 < HID) load_step(k0 + 32);   // overlap with frag reads + MFMA
        bf16x8 ah[2], al[2], bh[4], bl[4];
#pragma unroll
        for (int mb = 0; mb < 2; mb++) {
            ah[mb] = *(bf16x8*)&Ah[w * 128 + mb * 64 + lane][0];
            al[mb] = *(bf16x8*)&Al[w * 128 + mb * 64 + lane][0];
        }
#pragma unroll
        for (int nb = 0; nb < 4; nb++) {
            bh[nb] = *(bf16x8*)&Bh[nb * 64 + lane][0];
            bl[nb] = *(bf16x8*)&Bl[nb * 64 + lane][0];
        }
#pragma unroll
        for (int mb = 0; mb < 2; mb++)
#pragma unroll
            for (int nb = 0; nb < 4; nb++) {
                MM(ah[mb], bh[nb], acc[mb][nb]);
                MM(ah[mb], bl[nb], acc[mb][nb]);
                MM(al[mb], bh[nb], acc[mb][nb]);
            }
        __syncthreads();
    }
#pragma unroll
    for (int mb = 0; mb < 2; mb++)
#pragma unroll
        for (int r = 0; r < 4; r++) {
            int row = m0 + w * 32 + mb * 16 + kg * 4 + r;
#pragma unroll
            for (int nb = 0; nb < 4; nb++)
                Wx2[(size_t)row * C2 + n0 + nb * 16 + fr] = acc[mb][nb][r];
        }
}

// ---------------- k8: layer-2 scan p1 + wprep2 ----------------
__global__ __launch_bounds__(256) void k8_scan2_p1(const float* __restrict__ Wx2,
        const float* __restrict__ ts2, const int* __restrict__ perm2,
        float* __restrict__ cTA, float* __restrict__ cTB,
        float* __restrict__ SA, float* __restrict__ SB) {
    __shared__ float swA[4], swB[4];
    const int bid = blockIdx.x, t = threadIdx.x;
    if (bid >= 2048) { wprep_block(ts2, SA, SB, bid - 2048, t, swA, swB); return; }
    const int ch = bid & (CH - 1), h = bid >> 9;
    const int d = t, k0 = ch * CHR;
    const float tmax = ts2[h * NND + NND - 1];
    float aA = 0.f, aB = 0.f;
#pragma unroll
    for (int r = 0; r < CHR; r++) {
        float u = ts2[h * NND + k0 + r] - tmax;
        float wa = expf(u), wb = expf(LEAKY * u);
        int j = perm2[h * NND + k0 + r];
        float v = Wx2[(size_t)j * C2 + h * D2 + d];
        aA += wa * v; aB += wb * v;
    }
    cTA[(h * CH + ch) * D2 + d] = aA;
    cTB[(h * CH + ch) * D2 + d] = aB;
}

// ---------------- k10: layer-2 scan p3 ----------------
__global__ __launch_bounds__(256) void k10_scan2_p3(const float* __restrict__ Wx2,
        const float* __restrict__ ts2, const int* __restrict__ perm2,
        const float* __restrict__ cTA, const float* __restrict__ cTB,
        const float* __restrict__ TotA,
        float* __restrict__ A, float* __restrict__ B) {
    const int bid = blockIdx.x, t = threadIdx.x;
    const int ch = bid & (CH - 1), h = bid >> 9;
    const int d = t;
    const float tmax = ts2[h * NND + NND - 1];
    float runA = cTA[(h * CH + ch) * D2 + d];
    float runB = cTB[(h * CH + ch) * D2 + d];
    const float totA = TotA[h * D2 + d];
    const int k0 = ch * CHR;
    float v[CHR], wa[CHR], wb[CHR];
#pragma unroll
    for (int r = 0; r < CHR; r++) {
        float u = ts2[h * NND + k0 + r] - tmax;
        wa[r] = expf(u); wb[r] = expf(LEAKY * u);
        int j = perm2[h * NND + k0 + r];
        v[r] = Wx2[(size_t)j * C2 + h * D2 + d];
    }
#pragma unroll
    for (int r = 0; r < CHR; r++) {
        size_t o = ((size_t)(h * NP1 + k0 + r)) * D2 + d;
        A[o] = totA - runA;
        B[o] = runB;
        runA += wa[r] * v[r];
        runB += wb[r] * v[r];
    }
    if (ch == CH - 1) {
        size_t o = ((size_t)(h * NP1 + NND)) * D2 + d;
        A[o] = totA - runA;
        B[o] = runB;
    }
}

// ---------------- k11: lookup2 (head-mean + ELU + LayerNorm) ----------------
__global__ __launch_bounds__(256) void k11_lookup2(const float* __restrict__ es,
        const float* __restrict__ ts,
        const float* __restrict__ A, const float* __restrict__ B,
        const float* __restrict__ SA, const float* __restrict__ SB,
        const float* __restrict__ gamma, const float* __restrict__ betap,
        float* __restrict__ out) {
    __shared__ float red[4];
    const int i = blockIdx.x;
    const int t = threadIdx.x;
    const int wid = t >> 6, lane = t & 63;
    float acc = 0.f;
#pragma unroll
    for (int h = 0; h < HEADS; h++) {
        float c = es[h * NND + i];
        float tmax = ts[h * NND + NND - 1];
        float s = c + tmax;
        float m = (s >= 0.f) ? s : LEAKY * s;
        float al = expf(s - m);
        float be = expf(LEAKY * s - m);
        int k = lower_bound_f(ts + h * NND, -c);
        size_t o = ((size_t)(h * NP1 + k)) * D2 + t;
        float num = al * A[o] + be * B[o];
        float den = al * SA[h * NP1 + k] + be * SB[h * NP1 + k];
        acc += num / den;
    }
    acc *= 0.25f;
    float xv = (acc > 0.f) ? acc : expm1f(acc);
    float sv = wave_sum(xv);
    if (lane == 0) red[wid] = sv;
    __syncthreads();
    float mu = (red[0] + red[1] + red[2] + red[3]) * (1.f / 256.f);
    __syncthreads();
    float dv = xv - mu;
    float s2 = wave_sum(dv * dv);
    if (lane == 0) red[wid] = s2;
    __syncthreads();
    float var = (red[0] + red[1] + red[2] + red[3]) * (1.f / 256.f);
    out[i * D2 + t] = gamma[t] * dv * rsqrtf(var + LN_EPS) + betap[t];
}

extern "C" void kernel_launch(void* const* d_in, const int* in_sizes, int n_in,
                              void* d_out, int out_size, void* d_ws, size_t ws_size,
                              hipStream_t stream) {
    const float* x     = (const float*)d_in[0];
    const float* W1    = (const float*)d_in[1];
    const float* attn1 = (const float*)d_in[2];
    const float* W2    = (const float*)d_in[3];
    const float* attn2 = (const float*)d_in[4];
    const float* gamma = (const float*)d_in[5];
    const float* betap = (const float*)d_in[6];
    float* out = (float*)d_out;

    char* ws = (char*)d_ws;
    size_t off = 0;
    auto alloc = [&](size_t nbytes) -> void* {
        void* p = (void*)(ws + off);
        off += (nbytes + 255) & ~(size_t)255;
        return p;
    };

    float* Wx1 = (float*)alloc((size_t)NND * HID * 4);
    float* Wx2 = (float*)alloc((size_t)NND * C2 * 4);
    unsigned short* h1h = (unsigned short*)alloc((size_t)NND * HID * 2);
    unsigned short* h1l = (unsigned short*)alloc((size_t)NND * HID * 2);
    float* es1 = (float*)alloc((size_t)HEADS * NND * 4);
    float* et1 = (float*)alloc((size_t)HEADS * NND * 4);
    float* es2 = (float*)alloc((size_t)HEADS * NND * 4);
    float* et2 = (float*)alloc((size_t)HEADS * NND * 4);
    float* ts1 = (float*)alloc((size_t)HEADS * NND * 4);
    float* ts2 = (float*)alloc((size_t)HEADS * NND * 4);
    int* perm1 = (int*)alloc((size_t)HEADS * NND * 4);
    int* perm2 = (int*)alloc((size_t)HEADS * NND * 4);
    float* A   = (float*)alloc((size_t)HEADS * NP1 * D2 * 4);
    float* B   = (float*)alloc((size_t)HEADS * NP1 * D2 * 4);
    float* SA  = (float*)alloc((size_t)HEADS * NP1 * 4);
    float* SB  = (float*)alloc((size_t)HEADS * NP1 * 4);
    float* cTA = (float*)alloc((size_t)HEADS * CH * D2 * 4);
    float* cTB = (float*)alloc((size_t)HEADS * CH * D2 * 4);
    float* TotA = (float*)alloc((size_t)HEADS * D2 * 4);
    float* TotB = (float*)alloc((size_t)HEADS * D2 * 4);
    unsigned short* W2h = (unsigned short*)alloc((size_t)262144 * 2);
    unsigned short* W2l = (unsigned short*)alloc((size_t)262144 * 2);
    float* w_es = (float*)alloc((size_t)HEADS * HID * 4);
    float* w_et = (float*)alloc((size_t)HEADS * HID * 4);
    (void)ws_size; (void)in_sizes; (void)n_in; (void)out_size;

    // ---- layer 1 ----
    k1_gemm1_prep<<<1792, 256, 0, stream>>>(x, W1, attn1, W2, attn2,
                                            Wx1, es1, et1, W2h, W2l, w_es, w_et);
    k2_sort<<<256, 256, 0, stream>>>(et1, ts1, perm1);
    k3_scan1_p1<<<CH + 4, 256, 0, stream>>>(Wx1, ts1, perm1, cTA, cTB, SA, SB);
    k_scan_p2<<<64, 256, 0, stream>>>(cTA, cTB, TotA, TotB, 6);
    k5_scan1_p3<<<CH, 256, 0, stream>>>(Wx1, ts1, perm1, cTA, cTB, TotA, A, B);
    k6_lookup1<<<NND, 256, 0, stream>>>(es1, ts1, A, B, SA, SB, w_es, w_et,
                                        h1h, h1l, es2, et2);

    // ---- layer 2 ----
    k2_sort<<<256, 256, 0, stream>>>(et2, ts2, perm2);
    k7_gemm2<<<512, 256, 0, stream>>>(h1h, h1l, W2h, W2l, Wx2);
    k8_scan2_p1<<<2052, 256, 0, stream>>>(Wx2, ts2, perm2, cTA, cTB, SA, SB);
    k_scan_p2<<<256, 256, 0, stream>>>(cTA, cTB, TotA, TotB, 8);
    k10_scan2_p3<<<2048, 256, 0, stream>>>(Wx2, ts2, perm2, cTA, cTB, TotA, A, B);
    k11_lookup2<<<NND, 256, 0, stream>>>(es2, ts2, A, B, SA, SB, gamma, betap, out);
}